// Round 5
// baseline (472.052 us; speedup 1.0000x reference)
//
#include <hip/hip_runtime.h>

// Res_MCNN_branch2 on gfx950 — all convs f16 MFMA implicit-GEMM (16x16x32).
// R14 = R13 + g-split occupancy fix on conv2/conv4.
// conv2 diagnosed at 57% of MFMA peak with ~43% idle; limiter = 204 regs/wave
// (108 VGPR + 96 acc) -> 2 waves/SIMD. g-split halves acc (96->48) and frag
// window (96->48, 2-row slide) -> ~158 regs -> 3 waves/SIMD; MFMA count
// unchanged, K-loop runs twice (A-loads L1-hot, frag reads 48->72/wave,
// LDS pipe 11->17% — hidden). conv4 same (->~120 regs, 4 waves/SIMD).
// R11/R12 multi-tile REVERTED permanently: per-block footprint x4 thrashed
// L2 (32MB) -> write-allocate storm, 985MB FETCH. Keep blocks small.
// Layouts: P1 NHWC24, P2 NHWC56, X3 NHWC24. Frag K-spill into next pixel
// record is safe (zero weights there; 16-half zeroed LDS tail).
// conv4+conv5 fused (R13): q-lanes hold same pixel -> shfl_xor reduce + gray.

typedef _Float16 half_t;
typedef _Float16 half8 __attribute__((ext_vector_type(8)));
typedef float floatx4 __attribute__((ext_vector_type(4)));

#define IN_H 768
#define IN_W 1024
#define P1H 384
#define P1W 512
#define P2H 192
#define P2W 256

// workspace offsets (bytes)
#define OFF_P2 0ULL                 // f16 [8][192][256][56] = 44,040,192
#define OFF_P1 44040192ULL          // f16 [8][384][512][24] = 75,497,472
#define OFF_X3 44040192ULL          // reuse P1 region after conv2
#define OFF_W2 119537664ULL         // f16 [25][48][32] = 76,800 el
#define OFF_W3 119691264ULL         // f16 [25][32][64] = 102,400 el
#define OFF_W4 119896064ULL         // f16 [25][16][32] = 25,600 el
#define OFF_W1 119947264ULL         // f16 [7][32][32]  = 7,168 el

union PK4 { half_t h[4]; uint2 u; };
union U8 { half8 v; uint2 u[2]; };

// ---------------- weight pre-pack (fp32 OIHW -> f16 packed, linear) ----------------
__global__ __launch_bounds__(256) void pack_weights(
    const float* __restrict__ w2, const float* __restrict__ w3,
    const float* __restrict__ w4, const float* __restrict__ w1,
    half_t* __restrict__ wp2, half_t* __restrict__ wp3, half_t* __restrict__ wp4,
    half_t* __restrict__ wp1)
{
  int t = blockIdx.x * 256 + threadIdx.x;
  if (t < 38400) {                       // conv2: [25][48][32]
    int tap = t / 1536, r = t % 1536, oc = r >> 5, c = r & 31;
    float v = (oc < 40 && c < 20) ? w2[(oc * 20 + c) * 25 + tap] : 0.f;
    wp2[t] = (half_t)v;
  } else if (t < 89600) {                // conv3: [25][32][64]
    int u = t - 38400;
    int tap = u / 2048, r = u % 2048, oc = r >> 6, c = r & 63;
    float v = (oc < 20 && c < 40) ? w3[(oc * 40 + c) * 25 + tap] : 0.f;
    wp3[u] = (half_t)v;
  } else if (t < 102400) {               // conv4: [25][16][32]
    int u = t - 89600;
    int tap = u / 512, r = u % 512, oc = r >> 5, c = r & 31;
    float v = (oc < 10 && c < 20) ? w4[(oc * 20 + c) * 25 + tap] : 0.f;
    wp4[u] = (half_t)v;
  } else if (t < 109568) {               // conv1: [7][32][32], k = kx*4+c
    int u = t - 102400;
    int ky = u / 1024, r = u % 1024, oc = r >> 5, k = r & 31;
    int kx = k >> 2, c = k & 3;
    float v = (oc < 20 && c < 3 && kx < 7) ? w1[((oc * 3 + c) * 7 + ky) * 7 + kx] : 0.f;
    wp1[u] = (half_t)v;
  }
}

// ---------------- conv1 (3->20, 7x7, pad 3) MFMA + relu + pool -> P1 f16 NHWC24 ----------------
// 32-row tile, stage once (38x40 region, origin tx0-4 for float4 alignment),
// two K-loop passes p=0,1. Interior blocks: unguarded float4 staging.
__global__ __launch_bounds__(256) void conv1_mfma(
    const float* __restrict__ in, const half_t* __restrict__ wp,
    const float* __restrict__ bias, half_t* __restrict__ P1)
{
  __shared__ __align__(16) half_t ltile[38 * 40 * 4];   // 12160 B, row stride 40 px
  const int b = blockIdx.z, ty0 = blockIdx.y * 32, tx0 = blockIdx.x * 32;
  const int tid = threadIdx.x;
  const int HW1 = IN_H * IN_W;

  const float* p0 = in + (size_t)b * 3 * HW1;
  const bool interior = (blockIdx.x >= 1) && (blockIdx.x <= 30) &&
                        (blockIdx.y >= 1) && (blockIdx.y <= 22);
  if (interior) {
    for (int i = tid; i < 380; i += 256) {              // 38 rows x 10 float4
      int r = i / 10, c4 = i - r * 10;
      const float* pr = p0 + (size_t)(ty0 - 3 + r) * IN_W + (tx0 - 4 + 4 * c4);
      float4 v0 = *(const float4*)(pr);
      float4 v1 = *(const float4*)(pr + HW1);
      float4 v2 = *(const float4*)(pr + 2 * HW1);
      PK4 a0, a1, a2, a3;
      a0.h[0] = (half_t)v0.x; a0.h[1] = (half_t)v1.x; a0.h[2] = (half_t)v2.x; a0.h[3] = (half_t)0.f;
      a1.h[0] = (half_t)v0.y; a1.h[1] = (half_t)v1.y; a1.h[2] = (half_t)v2.y; a1.h[3] = (half_t)0.f;
      a2.h[0] = (half_t)v0.z; a2.h[1] = (half_t)v1.z; a2.h[2] = (half_t)v2.z; a2.h[3] = (half_t)0.f;
      a3.h[0] = (half_t)v0.w; a3.h[1] = (half_t)v1.w; a3.h[2] = (half_t)v2.w; a3.h[3] = (half_t)0.f;
      uint4* dst = (uint4*)(ltile + (r * 40 + 4 * c4) * 4);
      dst[0] = make_uint4(a0.u.x, a0.u.y, a1.u.x, a1.u.y);
      dst[1] = make_uint4(a2.u.x, a2.u.y, a3.u.x, a3.u.y);
    }
  } else {
    for (int i = tid; i < 1520; i += 256) {             // 38 rows x 40 cols, guarded
      int r = i / 40, c = i - r * 40;
      int gy = ty0 - 3 + r, gx = tx0 - 4 + c;
      float v0 = 0.f, v1 = 0.f, v2 = 0.f;
      if (gy >= 0 && gy < IN_H && (unsigned)gx < (unsigned)IN_W) {
        size_t o = (size_t)gy * IN_W + gx;
        v0 = p0[o];
        v1 = p0[o + HW1];
        v2 = p0[o + 2 * HW1];
      }
      PK4 pk;
      pk.h[0] = (half_t)v0; pk.h[1] = (half_t)v1;
      pk.h[2] = (half_t)v2; pk.h[3] = (half_t)0.f;
      *(uint2*)(ltile + (r * 40 + c) * 4) = pk.u;
    }
  }
  __syncthreads();

  const int wv = tid >> 6, ln = tid & 63, q = ln >> 4, nl = ln & 15;
  const int cbase = (2 * nl + 2 * q + 1) * 4;           // +1: tile origin tx0-4
  const half_t* wA = wp + nl * 32 + q * 8;

  floatx4 bv[2];
  #pragma unroll
  for (int mt = 0; mt < 2; ++mt)
    #pragma unroll
    for (int r = 0; r < 4; ++r) {
      int oc = mt * 16 + q * 4 + r;
      bv[mt][r] = (oc < 20) ? bias[oc] : 0.f;
    }
  const int pc = (tx0 >> 1) + nl;

  #pragma unroll
  for (int p = 0; p < 2; ++p) {
    const int rbase = p * 16 + 4 * wv;            // ltile row of this pass/wave
    U8 frag[4][2];
    #pragma unroll
    for (int d = 0; d < 4; ++d) {
      const half_t* rp = ltile + (rbase + d) * 160 + cbase;
      #pragma unroll
      for (int phx = 0; phx < 2; ++phx) {
        frag[d][phx].u[0] = *(const uint2*)(rp + phx * 4);
        frag[d][phx].u[1] = *(const uint2*)(rp + phx * 4 + 4);
      }
    }
    half8 Abuf[2][2];
    Abuf[0][0] = *(const half8*)(wA);
    Abuf[0][1] = *(const half8*)(wA + 512);
    floatx4 acc[2][8];
    #pragma unroll
    for (int mt = 0; mt < 2; ++mt)
      #pragma unroll
      for (int j = 0; j < 8; ++j) acc[mt][j] = (floatx4){0.f, 0.f, 0.f, 0.f};

    #pragma unroll
    for (int ky = 0; ky < 7; ++ky) {
      if (ky < 6) {
        Abuf[(ky + 1) & 1][0] = *(const half8*)(wA + (ky + 1) * 1024);
        Abuf[(ky + 1) & 1][1] = *(const half8*)(wA + (ky + 1) * 1024 + 512);
      }
      #pragma unroll
      for (int j = 0; j < 8; ++j) {
        const int g = j >> 2, ph = j & 3, phy = ph >> 1, phx = ph & 1;
        half8 B = frag[(2 * g + phy + ky) & 3][phx].v;
        acc[0][j] = __builtin_amdgcn_mfma_f32_16x16x32_f16(Abuf[ky & 1][0], B, acc[0][j], 0, 0, 0);
        acc[1][j] = __builtin_amdgcn_mfma_f32_16x16x32_f16(Abuf[ky & 1][1], B, acc[1][j], 0, 0, 0);
      }
      if (ky < 6) {                               // slide: ltile row rbase+ky+4 -> slot ky&3
        const half_t* rp = ltile + (rbase + ky + 4) * 160 + cbase;
        #pragma unroll
        for (int phx = 0; phx < 2; ++phx) {
          frag[ky & 3][phx].u[0] = *(const uint2*)(rp + phx * 4);
          frag[ky & 3][phx].u[1] = *(const uint2*)(rp + phx * 4 + 4);
        }
      }
    }

    const int pr0 = (ty0 >> 1) + 8 * p + 2 * wv;
    #pragma unroll
    for (int g = 0; g < 2; ++g) {
      size_t pxbase = (((size_t)b * P1H + pr0 + g) * P1W + pc) * 24;
      PK4 pk0;
      #pragma unroll
      for (int r = 0; r < 4; ++r) {
        float x = fmaxf(fmaxf(acc[0][g * 4 + 0][r], acc[0][g * 4 + 1][r]),
                        fmaxf(acc[0][g * 4 + 2][r], acc[0][g * 4 + 3][r]));
        pk0.h[r] = (half_t)fmaxf(x + bv[0][r], 0.f);
      }
      *(uint2*)(P1 + pxbase + q * 4) = pk0.u;           // oc 0..15
      if (q < 2) {                                      // oc 16..19 real, 20..23 = 0
        PK4 pk1;
        #pragma unroll
        for (int r = 0; r < 4; ++r) {
          float x = fmaxf(fmaxf(acc[1][g * 4 + 0][r], acc[1][g * 4 + 1][r]),
                          fmaxf(acc[1][g * 4 + 2][r], acc[1][g * 4 + 3][r]));
          pk1.h[r] = (half_t)fmaxf(x + bv[1][r], 0.f);
        }
        *(uint2*)(P1 + pxbase + 16 + q * 4) = pk1.u;
      }
    }
  }
}

// ---------------- conv2 (20->40, 5x5) MFMA + relu + pool -> P2 f16 NHWC56 ----------------
// g-split: two passes over the K-loop (g=0,1), each with acc[3][4] and a
// 2-row sliding frag window -> ~158 regs/wave -> 3 waves/SIMD (was 204 -> 2).
// P1 records 24 halves; frag q=3 spills into next record (zero weights).
__global__ __launch_bounds__(256, 3) void conv2_mfma(
    const half_t* __restrict__ P1, const half_t* __restrict__ wp,
    const float* __restrict__ bias, half_t* __restrict__ P2)
{
  __shared__ __align__(16) half_t lin[20 * 36 * 24 + 16];   // 34592 B (16-half zero tail)
  const int b = blockIdx.z, ty0 = blockIdx.y * 16, tx0 = blockIdx.x * 32;
  const int tid = threadIdx.x;
  if (tid < 16) lin[20 * 36 * 24 + tid] = (half_t)0.f;
  for (int i = tid; i < 2160; i += 256) {              // 720 px x 3 uint4
    int px = i / 3, part = i - px * 3;
    int row = px / 36, col = px - row * 36;
    int gy = ty0 - 2 + row, gx = tx0 - 2 + col;
    uint4 v = make_uint4(0, 0, 0, 0);
    if (gy >= 0 && gy < P1H && (unsigned)gx < (unsigned)P1W)
      v = *(const uint4*)(P1 + (((size_t)b * P1H + gy) * P1W + gx) * 24 + part * 8);
    *(uint4*)(lin + px * 24 + part * 8) = v;
  }
  __syncthreads();

  const int wv = tid >> 6, ln = tid & 63, q = ln >> 4, nl = ln & 15;
  const int cbase = 2 * nl * 24 + q * 8;               // + row*864 + c*24
  const half_t* wA = wp + nl * 32 + q * 8;
  floatx4 bv[3];
  #pragma unroll
  for (int mt = 0; mt < 3; ++mt)
    #pragma unroll
    for (int r = 0; r < 4; ++r) {
      int oc = mt * 16 + q * 4 + r;
      bv[mt][r] = (oc < 40) ? bias[oc] : 0.f;
    }
  const int pr0 = (ty0 >> 1) + 2 * wv;
  const int pc = (tx0 >> 1) + nl;

  #pragma unroll
  for (int g = 0; g < 2; ++g) {
    half8 frag[2][6];                                  // 2-row window
    #pragma unroll
    for (int d = 0; d < 2; ++d) {
      const half_t* rp = lin + (4 * wv + 2 * g + d) * 864 + cbase;
      #pragma unroll
      for (int c = 0; c < 6; ++c) frag[d][c] = *(const half8*)(rp + c * 24);
    }
    half8 Abuf[2][3];
    #pragma unroll
    for (int mt = 0; mt < 3; ++mt) Abuf[0][mt] = *(const half8*)(wA + mt * 512);
    floatx4 acc[3][4];
    #pragma unroll
    for (int mt = 0; mt < 3; ++mt)
      #pragma unroll
      for (int j = 0; j < 4; ++j) acc[mt][j] = (floatx4){0.f, 0.f, 0.f, 0.f};

    #pragma unroll
    for (int ky = 0; ky < 5; ++ky) {
      #pragma unroll
      for (int kx = 0; kx < 5; ++kx) {
        const int tap = ky * 5 + kx;
        if (tap < 24) {
          #pragma unroll
          for (int mt = 0; mt < 3; ++mt)
            Abuf[(tap + 1) & 1][mt] = *(const half8*)(wA + (tap + 1) * 1536 + mt * 512);
        }
        #pragma unroll
        for (int j = 0; j < 4; ++j) {
          const int phy = j >> 1, phx = j & 1;
          half8 B = frag[(phy + ky) & 1][kx + phx];
          acc[0][j] = __builtin_amdgcn_mfma_f32_16x16x32_f16(Abuf[tap & 1][0], B, acc[0][j], 0, 0, 0);
          acc[1][j] = __builtin_amdgcn_mfma_f32_16x16x32_f16(Abuf[tap & 1][1], B, acc[1][j], 0, 0, 0);
          acc[2][j] = __builtin_amdgcn_mfma_f32_16x16x32_f16(Abuf[tap & 1][2], B, acc[2][j], 0, 0, 0);
        }
      }
      if (ky < 4) {                                    // slide: row 4wv+2g+ky+2 -> slot ky&1
        const half_t* rp = lin + (4 * wv + 2 * g + ky + 2) * 864 + cbase;
        #pragma unroll
        for (int c = 0; c < 6; ++c) frag[ky & 1][c] = *(const half8*)(rp + c * 24);
      }
    }

    size_t pxbase = (((size_t)b * P2H + pr0 + g) * P2W + pc) * 56;
    #pragma unroll
    for (int mt = 0; mt < 3; ++mt) {
      PK4 pk;
      #pragma unroll
      for (int r = 0; r < 4; ++r) {
        float x = fmaxf(fmaxf(acc[mt][0][r], acc[mt][1][r]),
                        fmaxf(acc[mt][2][r], acc[mt][3][r]));
        pk.h[r] = (half_t)fmaxf(x + bv[mt][r], 0.f);   // oc 40..47: 0+0 -> 0 pad
      }
      *(uint2*)(P2 + pxbase + mt * 16 + q * 4) = pk.u;
    }
    if (q == 0)
      *(uint4*)(P2 + pxbase + 48) = make_uint4(0, 0, 0, 0);  // halves 48..55 = 0
  }
}

// ---------------- conv3 (40->20, 5x5) MFMA + relu -> X3 f16 NHWC24 ----------------
// P2 records 56 halves (40 real + 16 zero). Window frag[2][6][2cb] + A prefetch.
__global__ __launch_bounds__(256, 2) void conv3_mfma(
    const half_t* __restrict__ P2, const half_t* __restrict__ wp,
    const float* __restrict__ bias, half_t* __restrict__ X3)
{
  __shared__ __align__(16) half_t lin[12 * 36 * 56 + 16];   // 48416 B
  const int b = blockIdx.z, ty0 = blockIdx.y * 8, tx0 = blockIdx.x * 32;
  const int tid = threadIdx.x;
  if (tid < 16) lin[12 * 36 * 56 + tid] = (half_t)0.f;
  for (int i = tid; i < 3024; i += 256) {              // 432 px x 7 uint4
    int px = i / 7, part = i - px * 7;
    int row = px / 36, col = px - row * 36;
    int gy = ty0 - 2 + row, gx = tx0 - 2 + col;
    uint4 v = make_uint4(0, 0, 0, 0);
    if (gy >= 0 && gy < P2H && (unsigned)gx < (unsigned)P2W)
      v = *(const uint4*)(P2 + (((size_t)b * P2H + gy) * P2W + gx) * 56 + part * 8);
    *(uint4*)(lin + px * 56 + part * 8) = v;
  }
  __syncthreads();

  const int wv = tid >> 6, ln = tid & 63, q = ln >> 4, nl = ln & 15;
  const int cbase = 2 * nl * 56 + q * 8;               // + row*2016 + c*56 + cb*32
  half8 frag[2][6][2];
  #pragma unroll
  for (int c = 0; c < 6; ++c)
    #pragma unroll
    for (int cb = 0; cb < 2; ++cb) {
      frag[0][c][cb] = *(const half8*)(lin + (2 * wv + 0) * 2016 + cbase + c * 56 + cb * 32);
      frag[1][c][cb] = *(const half8*)(lin + (2 * wv + 1) * 2016 + cbase + c * 56 + cb * 32);
    }
  const half_t* wA = wp + nl * 64 + q * 8;
  half8 Abuf[2][2][2];                                 // [parity][mt][cb]
  #pragma unroll
  for (int mt = 0; mt < 2; ++mt)
    #pragma unroll
    for (int cb = 0; cb < 2; ++cb)
      Abuf[0][mt][cb] = *(const half8*)(wA + mt * 1024 + cb * 32);
  floatx4 acc[2][4];
  #pragma unroll
  for (int mt = 0; mt < 2; ++mt)
    #pragma unroll
    for (int j = 0; j < 4; ++j) acc[mt][j] = (floatx4){0.f, 0.f, 0.f, 0.f};

  #pragma unroll
  for (int ky = 0; ky < 5; ++ky) {
    #pragma unroll
    for (int kx = 0; kx < 5; ++kx) {
      const int tap = ky * 5 + kx;
      if (tap < 24) {
        #pragma unroll
        for (int mt = 0; mt < 2; ++mt)
          #pragma unroll
          for (int cb = 0; cb < 2; ++cb)
            Abuf[(tap + 1) & 1][mt][cb] =
                *(const half8*)(wA + (tap + 1) * 2048 + mt * 1024 + cb * 32);
      }
      #pragma unroll
      for (int cb = 0; cb < 2; ++cb)
        #pragma unroll
        for (int j = 0; j < 4; ++j) {
          const int phy = j >> 1, phx = j & 1;
          half8 B = frag[(ky + phy) & 1][kx + phx][cb];
          acc[0][j] = __builtin_amdgcn_mfma_f32_16x16x32_f16(Abuf[tap & 1][0][cb], B, acc[0][j], 0, 0, 0);
          acc[1][j] = __builtin_amdgcn_mfma_f32_16x16x32_f16(Abuf[tap & 1][1][cb], B, acc[1][j], 0, 0, 0);
        }
    }
    if (ky < 4) {
      const half_t* rp = lin + (2 * wv + ky + 2) * 2016 + cbase;
      #pragma unroll
      for (int c = 0; c < 6; ++c)
        #pragma unroll
        for (int cb = 0; cb < 2; ++cb)
          frag[ky & 1][c][cb] = *(const half8*)(rp + c * 56 + cb * 32);
    }
  }

  floatx4 bv[2];
  #pragma unroll
  for (int mt = 0; mt < 2; ++mt)
    #pragma unroll
    for (int r = 0; r < 4; ++r) {
      int oc = mt * 16 + q * 4 + r;
      bv[mt][r] = (oc < 20) ? bias[oc] : 0.f;
    }
  #pragma unroll
  for (int j = 0; j < 4; ++j) {
    const int phy = j >> 1, phx = j & 1;
    int y = ty0 + 2 * wv + phy, x = tx0 + 2 * nl + phx;
    size_t pxbase = (((size_t)b * P2H + y) * P2W + x) * 24;
    #pragma unroll
    for (int mt = 0; mt < 2; ++mt) {
      if (mt == 1 && q >= 2) continue;                 // record is 24 halves
      floatx4 v = acc[mt][j];
      PK4 pk;
      #pragma unroll
      for (int r = 0; r < 4; ++r) pk.h[r] = (half_t)fmaxf(v[r] + bv[mt][r], 0.f);
      *(uint2*)(X3 + pxbase + mt * 16 + q * 4) = pk.u; // oc 20..23 auto-zero
    }
  }
}

// ---------------- conv4 (20->10, 5x5) + conv5 (10->1, 1x1) + gray residual + relu ----------------
// g-split: acc[4] + 2-row frag window -> ~120 regs -> up to 4 waves/SIMD.
// Fused epilogue per g: q-lanes hold the same pixel (different oc) -> per-lane
// w5 partial, shfl_xor(16)+shfl_xor(32) reduce, q==0 adds gray + writes out.
__global__ __launch_bounds__(256, 3) void conv4_mfma(
    const half_t* __restrict__ X3, const half_t* __restrict__ wp,
    const float* __restrict__ bias, const float* __restrict__ w5,
    const float* __restrict__ b5, const float* __restrict__ in,
    float* __restrict__ out)
{
  __shared__ __align__(16) half_t lin[20 * 36 * 24 + 16];   // 34592 B
  const int b = blockIdx.z, ty0 = blockIdx.y * 16, tx0 = blockIdx.x * 32;
  const int tid = threadIdx.x;
  if (tid < 16) lin[20 * 36 * 24 + tid] = (half_t)0.f;
  for (int i = tid; i < 2160; i += 256) {
    int px = i / 3, part = i - px * 3;
    int row = px / 36, col = px - row * 36;
    int gy = ty0 - 2 + row, gx = tx0 - 2 + col;
    uint4 v = make_uint4(0, 0, 0, 0);
    if (gy >= 0 && gy < P2H && (unsigned)gx < (unsigned)P2W)
      v = *(const uint4*)(X3 + (((size_t)b * P2H + gy) * P2W + gx) * 24 + part * 8);
    *(uint4*)(lin + px * 24 + part * 8) = v;
  }
  __syncthreads();

  const int wv = tid >> 6, ln = tid & 63, q = ln >> 4, nl = ln & 15;
  const int cbase = 2 * nl * 24 + q * 8;
  const half_t* wA = wp + nl * 32 + q * 8;
  float bv[4], w5v[4];
  #pragma unroll
  for (int r = 0; r < 4; ++r) {
    int oc = q * 4 + r;
    bv[r]  = (oc < 10) ? bias[oc] : 0.f;
    w5v[r] = (oc < 10) ? w5[oc] : 0.f;
  }
  const float b5v = b5[0];
  const float* inb = in + (size_t)b * 3 * (IN_H * IN_W);

  #pragma unroll
  for (int g = 0; g < 2; ++g) {
    half8 frag[2][6];
    #pragma unroll
    for (int d = 0; d < 2; ++d) {
      const half_t* rp = lin + (4 * wv + 2 * g + d) * 864 + cbase;
      #pragma unroll
      for (int c = 0; c < 6; ++c) frag[d][c] = *(const half8*)(rp + c * 24);
    }
    half8 Abuf[2];
    Abuf[0] = *(const half8*)(wA);
    floatx4 acc[4];
    #pragma unroll
    for (int j = 0; j < 4; ++j) acc[j] = (floatx4){0.f, 0.f, 0.f, 0.f};

    #pragma unroll
    for (int ky = 0; ky < 5; ++ky) {
      #pragma unroll
      for (int kx = 0; kx < 5; ++kx) {
        const int tap = ky * 5 + kx;
        if (tap < 24) Abuf[(tap + 1) & 1] = *(const half8*)(wA + (tap + 1) * 512);
        #pragma unroll
        for (int j = 0; j < 4; ++j) {
          const int phy = j >> 1, phx = j & 1;
          half8 B = frag[(phy + ky) & 1][kx + phx];
          acc[j] = __builtin_amdgcn_mfma_f32_16x16x32_f16(Abuf[tap & 1], B, acc[j], 0, 0, 0);
        }
      }
      if (ky < 4) {
        const half_t* rp = lin + (4 * wv + 2 * g + ky + 2) * 864 + cbase;
        #pragma unroll
        for (int c = 0; c < 6; ++c) frag[ky & 1][c] = *(const half8*)(rp + c * 24);
      }
    }

    #pragma unroll
    for (int phy = 0; phy < 2; ++phy) {
      const int y = ty0 + 4 * wv + 2 * g + phy;
      const int x0 = tx0 + 2 * nl;                     // phx=0 pixel; phx=1 is x0+1
      float s0 = 0.f, s1 = 0.f;
      #pragma unroll
      for (int r = 0; r < 4; ++r) {
        s0 += w5v[r] * fmaxf(acc[2 * phy + 0][r] + bv[r], 0.f);
        s1 += w5v[r] * fmaxf(acc[2 * phy + 1][r] + bv[r], 0.f);
      }
      s0 += __shfl_xor(s0, 16); s0 += __shfl_xor(s0, 32);
      s1 += __shfl_xor(s1, 16); s1 += __shfl_xor(s1, 32);
      if (q == 0) {
        // gray bilinear: input rows 4y+1,4y+2; cols 4x+1,4x+2 for x = x0, x0+1.
        const size_t cb = (size_t)(4 * y + 1) * IN_W + 4 * x0;
        float g0 = 0.f, g1 = 0.f;
        #pragma unroll
        for (int ch = 0; ch < 3; ++ch) {
          const float coef = (ch == 0) ? 0.299f : ((ch == 1) ? 0.587f : 0.114f);
          const float* qp = inb + (size_t)ch * (IN_H * IN_W);
          float4 a0 = *(const float4*)(qp + cb);
          float4 a1 = *(const float4*)(qp + cb + 4);
          float4 d0 = *(const float4*)(qp + cb + IN_W);
          float4 d1 = *(const float4*)(qp + cb + IN_W + 4);
          g0 += coef * (a0.y + a0.z + d0.y + d0.z);
          g1 += coef * (a1.y + a1.z + d1.y + d1.z);
        }
        float o0 = fmaxf(s0 + b5v + fmaxf(g0 * 0.25f, 0.f), 0.f);
        float o1 = fmaxf(s1 + b5v + fmaxf(g1 * 0.25f, 0.f), 0.f);
        *(float2*)(out + ((size_t)b * P2H + y) * P2W + x0) = make_float2(o0, o1);
      }
    }
  }
}

extern "C" void kernel_launch(void* const* d_in, const int* in_sizes, int n_in,
                              void* d_out, int out_size, void* d_ws, size_t ws_size,
                              hipStream_t stream) {
  const float* input = (const float*)d_in[0];
  const float* w1 = (const float*)d_in[1];  const float* b1 = (const float*)d_in[2];
  const float* w2 = (const float*)d_in[3];  const float* b2 = (const float*)d_in[4];
  const float* w3 = (const float*)d_in[5];  const float* b3 = (const float*)d_in[6];
  const float* w4 = (const float*)d_in[7];  const float* b4 = (const float*)d_in[8];
  const float* w5 = (const float*)d_in[9];  const float* b5 = (const float*)d_in[10];
  float* out = (float*)d_out;
  char* ws = (char*)d_ws;

  half_t* P2h = (half_t*)(ws + OFF_P2);
  half_t* P1h = (half_t*)(ws + OFF_P1);
  half_t* X3h = (half_t*)(ws + OFF_X3);
  half_t* wp2 = (half_t*)(ws + OFF_W2);
  half_t* wp3 = (half_t*)(ws + OFF_W3);
  half_t* wp4 = (half_t*)(ws + OFF_W4);
  half_t* wp1 = (half_t*)(ws + OFF_W1);

  pack_weights<<<432, 256, 0, stream>>>(w2, w3, w4, w1, wp2, wp3, wp4, wp1);
  conv1_mfma<<<dim3(32, 24, 8), 256, 0, stream>>>(input, wp1, b1, P1h);
  conv2_mfma<<<dim3(16, 24, 8), 256, 0, stream>>>(P1h, wp2, b2, P2h);
  conv3_mfma<<<dim3(8, 24, 8), 256, 0, stream>>>(P2h, wp3, b3, X3h);
  conv4_mfma<<<dim3(8, 12, 8), 256, 0, stream>>>(X3h, wp4, b4, w5, b5, input, out);
}

// Round 6
// 413.848 us; speedup vs baseline: 1.1406x; 1.1406x over previous
//
#include <hip/hip_runtime.h>

// Res_MCNN_branch2 on gfx950 — all convs f16 MFMA implicit-GEMM (16x16x32).
// R15 = R13 structure with conv2/conv4 re-parameterized to 2 conv rows/wave
// (was 4): window frag[2][6] (48 regs, was 96), acc[3][4] (48, was 96), j=4,
// block covers 8 rows (grid y x2). Total MFMA unchanged; per-wave regs ~147
// (< R13's proven 204) -> 3 waves/SIMD. SINGLE K-loop + SINGLE epilogue per
// wave — the R14 serial-g-loop (cross-K-loop liveness -> scratch spill:
// WRITE 43->277 MB, VGPR squeezed to 84) is the forbidden shape.
// Failure ledger: R11 gload_lds DMA (22x FETCH, no lane coalesce on 48B
// records), R12 reg-staging multi-tile (spill/L2 thrash), R14 g-split (spill).
// Rule: never add K-loop-crossing liveness to conv2; only SHRINK state.
// Layouts: P1 NHWC24, P2 NHWC56, X3 NHWC24. Frag K-spill into next pixel
// record safe (zero weight rows; 16-half zeroed LDS tail).
// conv4+conv5 fused (R13): q-lanes hold same pixel -> shfl_xor reduce + gray.

typedef _Float16 half_t;
typedef _Float16 half8 __attribute__((ext_vector_type(8)));
typedef float floatx4 __attribute__((ext_vector_type(4)));

#define IN_H 768
#define IN_W 1024
#define P1H 384
#define P1W 512
#define P2H 192
#define P2W 256

// workspace offsets (bytes)
#define OFF_P2 0ULL                 // f16 [8][192][256][56] = 44,040,192
#define OFF_P1 44040192ULL          // f16 [8][384][512][24] = 75,497,472
#define OFF_X3 44040192ULL          // reuse P1 region after conv2
#define OFF_W2 119537664ULL         // f16 [25][48][32] = 76,800 el
#define OFF_W3 119691264ULL         // f16 [25][32][64] = 102,400 el
#define OFF_W4 119896064ULL         // f16 [25][16][32] = 25,600 el
#define OFF_W1 119947264ULL         // f16 [7][32][32]  = 7,168 el

union PK4 { half_t h[4]; uint2 u; };
union U8 { half8 v; uint2 u[2]; };

// ---------------- weight pre-pack (fp32 OIHW -> f16 packed, linear) ----------------
__global__ __launch_bounds__(256) void pack_weights(
    const float* __restrict__ w2, const float* __restrict__ w3,
    const float* __restrict__ w4, const float* __restrict__ w1,
    half_t* __restrict__ wp2, half_t* __restrict__ wp3, half_t* __restrict__ wp4,
    half_t* __restrict__ wp1)
{
  int t = blockIdx.x * 256 + threadIdx.x;
  if (t < 38400) {                       // conv2: [25][48][32]
    int tap = t / 1536, r = t % 1536, oc = r >> 5, c = r & 31;
    float v = (oc < 40 && c < 20) ? w2[(oc * 20 + c) * 25 + tap] : 0.f;
    wp2[t] = (half_t)v;
  } else if (t < 89600) {                // conv3: [25][32][64]
    int u = t - 38400;
    int tap = u / 2048, r = u % 2048, oc = r >> 6, c = r & 63;
    float v = (oc < 20 && c < 40) ? w3[(oc * 40 + c) * 25 + tap] : 0.f;
    wp3[u] = (half_t)v;
  } else if (t < 102400) {               // conv4: [25][16][32]
    int u = t - 89600;
    int tap = u / 512, r = u % 512, oc = r >> 5, c = r & 31;
    float v = (oc < 10 && c < 20) ? w4[(oc * 20 + c) * 25 + tap] : 0.f;
    wp4[u] = (half_t)v;
  } else if (t < 109568) {               // conv1: [7][32][32], k = kx*4+c
    int u = t - 102400;
    int ky = u / 1024, r = u % 1024, oc = r >> 5, k = r & 31;
    int kx = k >> 2, c = k & 3;
    float v = (oc < 20 && c < 3 && kx < 7) ? w1[((oc * 3 + c) * 7 + ky) * 7 + kx] : 0.f;
    wp1[u] = (half_t)v;
  }
}

// ---------------- conv1 (3->20, 7x7, pad 3) MFMA + relu + pool -> P1 f16 NHWC24 ----------------
// 32-row tile, stage once (38x40 region, origin tx0-4 for float4 alignment),
// two K-loop passes p=0,1. Interior blocks: unguarded float4 staging.
__global__ __launch_bounds__(256) void conv1_mfma(
    const float* __restrict__ in, const half_t* __restrict__ wp,
    const float* __restrict__ bias, half_t* __restrict__ P1)
{
  __shared__ __align__(16) half_t ltile[38 * 40 * 4];   // 12160 B, row stride 40 px
  const int b = blockIdx.z, ty0 = blockIdx.y * 32, tx0 = blockIdx.x * 32;
  const int tid = threadIdx.x;
  const int HW1 = IN_H * IN_W;

  const float* p0 = in + (size_t)b * 3 * HW1;
  const bool interior = (blockIdx.x >= 1) && (blockIdx.x <= 30) &&
                        (blockIdx.y >= 1) && (blockIdx.y <= 22);
  if (interior) {
    for (int i = tid; i < 380; i += 256) {              // 38 rows x 10 float4
      int r = i / 10, c4 = i - r * 10;
      const float* pr = p0 + (size_t)(ty0 - 3 + r) * IN_W + (tx0 - 4 + 4 * c4);
      float4 v0 = *(const float4*)(pr);
      float4 v1 = *(const float4*)(pr + HW1);
      float4 v2 = *(const float4*)(pr + 2 * HW1);
      PK4 a0, a1, a2, a3;
      a0.h[0] = (half_t)v0.x; a0.h[1] = (half_t)v1.x; a0.h[2] = (half_t)v2.x; a0.h[3] = (half_t)0.f;
      a1.h[0] = (half_t)v0.y; a1.h[1] = (half_t)v1.y; a1.h[2] = (half_t)v2.y; a1.h[3] = (half_t)0.f;
      a2.h[0] = (half_t)v0.z; a2.h[1] = (half_t)v1.z; a2.h[2] = (half_t)v2.z; a2.h[3] = (half_t)0.f;
      a3.h[0] = (half_t)v0.w; a3.h[1] = (half_t)v1.w; a3.h[2] = (half_t)v2.w; a3.h[3] = (half_t)0.f;
      uint4* dst = (uint4*)(ltile + (r * 40 + 4 * c4) * 4);
      dst[0] = make_uint4(a0.u.x, a0.u.y, a1.u.x, a1.u.y);
      dst[1] = make_uint4(a2.u.x, a2.u.y, a3.u.x, a3.u.y);
    }
  } else {
    for (int i = tid; i < 1520; i += 256) {             // 38 rows x 40 cols, guarded
      int r = i / 40, c = i - r * 40;
      int gy = ty0 - 3 + r, gx = tx0 - 4 + c;
      float v0 = 0.f, v1 = 0.f, v2 = 0.f;
      if (gy >= 0 && gy < IN_H && (unsigned)gx < (unsigned)IN_W) {
        size_t o = (size_t)gy * IN_W + gx;
        v0 = p0[o];
        v1 = p0[o + HW1];
        v2 = p0[o + 2 * HW1];
      }
      PK4 pk;
      pk.h[0] = (half_t)v0; pk.h[1] = (half_t)v1;
      pk.h[2] = (half_t)v2; pk.h[3] = (half_t)0.f;
      *(uint2*)(ltile + (r * 40 + c) * 4) = pk.u;
    }
  }
  __syncthreads();

  const int wv = tid >> 6, ln = tid & 63, q = ln >> 4, nl = ln & 15;
  const int cbase = (2 * nl + 2 * q + 1) * 4;           // +1: tile origin tx0-4
  const half_t* wA = wp + nl * 32 + q * 8;

  floatx4 bv[2];
  #pragma unroll
  for (int mt = 0; mt < 2; ++mt)
    #pragma unroll
    for (int r = 0; r < 4; ++r) {
      int oc = mt * 16 + q * 4 + r;
      bv[mt][r] = (oc < 20) ? bias[oc] : 0.f;
    }
  const int pc = (tx0 >> 1) + nl;

  #pragma unroll
  for (int p = 0; p < 2; ++p) {
    const int rbase = p * 16 + 4 * wv;            // ltile row of this pass/wave
    U8 frag[4][2];
    #pragma unroll
    for (int d = 0; d < 4; ++d) {
      const half_t* rp = ltile + (rbase + d) * 160 + cbase;
      #pragma unroll
      for (int phx = 0; phx < 2; ++phx) {
        frag[d][phx].u[0] = *(const uint2*)(rp + phx * 4);
        frag[d][phx].u[1] = *(const uint2*)(rp + phx * 4 + 4);
      }
    }
    half8 Abuf[2][2];
    Abuf[0][0] = *(const half8*)(wA);
    Abuf[0][1] = *(const half8*)(wA + 512);
    floatx4 acc[2][8];
    #pragma unroll
    for (int mt = 0; mt < 2; ++mt)
      #pragma unroll
      for (int j = 0; j < 8; ++j) acc[mt][j] = (floatx4){0.f, 0.f, 0.f, 0.f};

    #pragma unroll
    for (int ky = 0; ky < 7; ++ky) {
      if (ky < 6) {
        Abuf[(ky + 1) & 1][0] = *(const half8*)(wA + (ky + 1) * 1024);
        Abuf[(ky + 1) & 1][1] = *(const half8*)(wA + (ky + 1) * 1024 + 512);
      }
      #pragma unroll
      for (int j = 0; j < 8; ++j) {
        const int g = j >> 2, ph = j & 3, phy = ph >> 1, phx = ph & 1;
        half8 B = frag[(2 * g + phy + ky) & 3][phx].v;
        acc[0][j] = __builtin_amdgcn_mfma_f32_16x16x32_f16(Abuf[ky & 1][0], B, acc[0][j], 0, 0, 0);
        acc[1][j] = __builtin_amdgcn_mfma_f32_16x16x32_f16(Abuf[ky & 1][1], B, acc[1][j], 0, 0, 0);
      }
      if (ky < 6) {                               // slide: ltile row rbase+ky+4 -> slot ky&3
        const half_t* rp = ltile + (rbase + ky + 4) * 160 + cbase;
        #pragma unroll
        for (int phx = 0; phx < 2; ++phx) {
          frag[ky & 3][phx].u[0] = *(const uint2*)(rp + phx * 4);
          frag[ky & 3][phx].u[1] = *(const uint2*)(rp + phx * 4 + 4);
        }
      }
    }

    const int pr0 = (ty0 >> 1) + 8 * p + 2 * wv;
    #pragma unroll
    for (int g = 0; g < 2; ++g) {
      size_t pxbase = (((size_t)b * P1H + pr0 + g) * P1W + pc) * 24;
      PK4 pk0;
      #pragma unroll
      for (int r = 0; r < 4; ++r) {
        float x = fmaxf(fmaxf(acc[0][g * 4 + 0][r], acc[0][g * 4 + 1][r]),
                        fmaxf(acc[0][g * 4 + 2][r], acc[0][g * 4 + 3][r]));
        pk0.h[r] = (half_t)fmaxf(x + bv[0][r], 0.f);
      }
      *(uint2*)(P1 + pxbase + q * 4) = pk0.u;           // oc 0..15
      if (q < 2) {                                      // oc 16..19 real, 20..23 = 0
        PK4 pk1;
        #pragma unroll
        for (int r = 0; r < 4; ++r) {
          float x = fmaxf(fmaxf(acc[1][g * 4 + 0][r], acc[1][g * 4 + 1][r]),
                          fmaxf(acc[1][g * 4 + 2][r], acc[1][g * 4 + 3][r]));
          pk1.h[r] = (half_t)fmaxf(x + bv[1][r], 0.f);
        }
        *(uint2*)(P1 + pxbase + 16 + q * 4) = pk1.u;
      }
    }
  }
}

// ---------------- conv2 (20->40, 5x5) MFMA + relu + pool -> P2 f16 NHWC56 ----------------
// 2 conv rows/wave: block = 8 conv rows, wave wv rows ty0+2wv+{0,1}.
// Window frag[2][6] (slot (phy+ky)&1), acc[3][4], j = phy*2+phx.
// P1 records 24 halves; frag q=3 spills into next record (zero weights).
__global__ __launch_bounds__(256, 3) void conv2_mfma(
    const half_t* __restrict__ P1, const half_t* __restrict__ wp,
    const float* __restrict__ bias, half_t* __restrict__ P2)
{
  __shared__ __align__(16) half_t lin[12 * 36 * 24 + 16];   // 20768 B (16-half zero tail)
  const int b = blockIdx.z, ty0 = blockIdx.y * 8, tx0 = blockIdx.x * 32;
  const int tid = threadIdx.x;
  if (tid < 16) lin[12 * 36 * 24 + tid] = (half_t)0.f;
  for (int i = tid; i < 1296; i += 256) {              // 432 px x 3 uint4
    int px = i / 3, part = i - px * 3;
    int row = px / 36, col = px - row * 36;
    int gy = ty0 - 2 + row, gx = tx0 - 2 + col;
    uint4 v = make_uint4(0, 0, 0, 0);
    if (gy >= 0 && gy < P1H && (unsigned)gx < (unsigned)P1W)
      v = *(const uint4*)(P1 + (((size_t)b * P1H + gy) * P1W + gx) * 24 + part * 8);
    *(uint4*)(lin + px * 24 + part * 8) = v;
  }
  __syncthreads();

  const int wv = tid >> 6, ln = tid & 63, q = ln >> 4, nl = ln & 15;
  const int cbase = 2 * nl * 24 + q * 8;               // + row*864 + c*24
  half8 frag[2][6];
  #pragma unroll
  for (int d = 0; d < 2; ++d) {
    const half_t* rp = lin + (2 * wv + d) * 864 + cbase;
    #pragma unroll
    for (int c = 0; c < 6; ++c) frag[d][c] = *(const half8*)(rp + c * 24);
  }
  const half_t* wA = wp + nl * 32 + q * 8;
  half8 Abuf[2][3];
  #pragma unroll
  for (int mt = 0; mt < 3; ++mt) Abuf[0][mt] = *(const half8*)(wA + mt * 512);
  floatx4 acc[3][4];
  #pragma unroll
  for (int mt = 0; mt < 3; ++mt)
    #pragma unroll
    for (int j = 0; j < 4; ++j) acc[mt][j] = (floatx4){0.f, 0.f, 0.f, 0.f};

  #pragma unroll
  for (int ky = 0; ky < 5; ++ky) {
    #pragma unroll
    for (int kx = 0; kx < 5; ++kx) {
      const int tap = ky * 5 + kx;
      if (tap < 24) {
        #pragma unroll
        for (int mt = 0; mt < 3; ++mt)
          Abuf[(tap + 1) & 1][mt] = *(const half8*)(wA + (tap + 1) * 1536 + mt * 512);
      }
      #pragma unroll
      for (int j = 0; j < 4; ++j) {
        const int phy = j >> 1, phx = j & 1;
        half8 B = frag[(phy + ky) & 1][kx + phx];
        acc[0][j] = __builtin_amdgcn_mfma_f32_16x16x32_f16(Abuf[tap & 1][0], B, acc[0][j], 0, 0, 0);
        acc[1][j] = __builtin_amdgcn_mfma_f32_16x16x32_f16(Abuf[tap & 1][1], B, acc[1][j], 0, 0, 0);
        acc[2][j] = __builtin_amdgcn_mfma_f32_16x16x32_f16(Abuf[tap & 1][2], B, acc[2][j], 0, 0, 0);
      }
    }
    if (ky < 4) {                                      // slide: row 2wv+ky+2 -> slot ky&1
      const half_t* rp = lin + (2 * wv + ky + 2) * 864 + cbase;
      #pragma unroll
      for (int c = 0; c < 6; ++c) frag[ky & 1][c] = *(const half8*)(rp + c * 24);
    }
  }

  floatx4 bv[3];
  #pragma unroll
  for (int mt = 0; mt < 3; ++mt)
    #pragma unroll
    for (int r = 0; r < 4; ++r) {
      int oc = mt * 16 + q * 4 + r;
      bv[mt][r] = (oc < 40) ? bias[oc] : 0.f;
    }
  const int pr = (ty0 >> 1) + wv;                      // pooled row of this wave
  const int pc = (tx0 >> 1) + nl;
  size_t pxbase = (((size_t)b * P2H + pr) * P2W + pc) * 56;
  #pragma unroll
  for (int mt = 0; mt < 3; ++mt) {
    PK4 pk;
    #pragma unroll
    for (int r = 0; r < 4; ++r) {
      float x = fmaxf(fmaxf(acc[mt][0][r], acc[mt][1][r]),
                      fmaxf(acc[mt][2][r], acc[mt][3][r]));
      pk.h[r] = (half_t)fmaxf(x + bv[mt][r], 0.f);     // oc 40..47: 0+0 -> 0 pad
    }
    *(uint2*)(P2 + pxbase + mt * 16 + q * 4) = pk.u;
  }
  if (q == 0)
    *(uint4*)(P2 + pxbase + 48) = make_uint4(0, 0, 0, 0);  // halves 48..55 = 0
}

// ---------------- conv3 (40->20, 5x5) MFMA + relu -> X3 f16 NHWC24 ----------------
// P2 records 56 halves (40 real + 16 zero). Window frag[2][6][2cb] + A prefetch.
__global__ __launch_bounds__(256, 2) void conv3_mfma(
    const half_t* __restrict__ P2, const half_t* __restrict__ wp,
    const float* __restrict__ bias, half_t* __restrict__ X3)
{
  __shared__ __align__(16) half_t lin[12 * 36 * 56 + 16];   // 48416 B
  const int b = blockIdx.z, ty0 = blockIdx.y * 8, tx0 = blockIdx.x * 32;
  const int tid = threadIdx.x;
  if (tid < 16) lin[12 * 36 * 56 + tid] = (half_t)0.f;
  for (int i = tid; i < 3024; i += 256) {              // 432 px x 7 uint4
    int px = i / 7, part = i - px * 7;
    int row = px / 36, col = px - row * 36;
    int gy = ty0 - 2 + row, gx = tx0 - 2 + col;
    uint4 v = make_uint4(0, 0, 0, 0);
    if (gy >= 0 && gy < P2H && (unsigned)gx < (unsigned)P2W)
      v = *(const uint4*)(P2 + (((size_t)b * P2H + gy) * P2W + gx) * 56 + part * 8);
    *(uint4*)(lin + px * 56 + part * 8) = v;
  }
  __syncthreads();

  const int wv = tid >> 6, ln = tid & 63, q = ln >> 4, nl = ln & 15;
  const int cbase = 2 * nl * 56 + q * 8;               // + row*2016 + c*56 + cb*32
  half8 frag[2][6][2];
  #pragma unroll
  for (int c = 0; c < 6; ++c)
    #pragma unroll
    for (int cb = 0; cb < 2; ++cb) {
      frag[0][c][cb] = *(const half8*)(lin + (2 * wv + 0) * 2016 + cbase + c * 56 + cb * 32);
      frag[1][c][cb] = *(const half8*)(lin + (2 * wv + 1) * 2016 + cbase + c * 56 + cb * 32);
    }
  const half_t* wA = wp + nl * 64 + q * 8;
  half8 Abuf[2][2][2];                                 // [parity][mt][cb]
  #pragma unroll
  for (int mt = 0; mt < 2; ++mt)
    #pragma unroll
    for (int cb = 0; cb < 2; ++cb)
      Abuf[0][mt][cb] = *(const half8*)(wA + mt * 1024 + cb * 32);
  floatx4 acc[2][4];
  #pragma unroll
  for (int mt = 0; mt < 2; ++mt)
    #pragma unroll
    for (int j = 0; j < 4; ++j) acc[mt][j] = (floatx4){0.f, 0.f, 0.f, 0.f};

  #pragma unroll
  for (int ky = 0; ky < 5; ++ky) {
    #pragma unroll
    for (int kx = 0; kx < 5; ++kx) {
      const int tap = ky * 5 + kx;
      if (tap < 24) {
        #pragma unroll
        for (int mt = 0; mt < 2; ++mt)
          #pragma unroll
          for (int cb = 0; cb < 2; ++cb)
            Abuf[(tap + 1) & 1][mt][cb] =
                *(const half8*)(wA + (tap + 1) * 2048 + mt * 1024 + cb * 32);
      }
      #pragma unroll
      for (int cb = 0; cb < 2; ++cb)
        #pragma unroll
        for (int j = 0; j < 4; ++j) {
          const int phy = j >> 1, phx = j & 1;
          half8 B = frag[(ky + phy) & 1][kx + phx][cb];
          acc[0][j] = __builtin_amdgcn_mfma_f32_16x16x32_f16(Abuf[tap & 1][0][cb], B, acc[0][j], 0, 0, 0);
          acc[1][j] = __builtin_amdgcn_mfma_f32_16x16x32_f16(Abuf[tap & 1][1][cb], B, acc[1][j], 0, 0, 0);
        }
    }
    if (ky < 4) {
      const half_t* rp = lin + (2 * wv + ky + 2) * 2016 + cbase;
      #pragma unroll
      for (int c = 0; c < 6; ++c)
        #pragma unroll
        for (int cb = 0; cb < 2; ++cb)
          frag[ky & 1][c][cb] = *(const half8*)(rp + c * 56 + cb * 32);
    }
  }

  floatx4 bv[2];
  #pragma unroll
  for (int mt = 0; mt < 2; ++mt)
    #pragma unroll
    for (int r = 0; r < 4; ++r) {
      int oc = mt * 16 + q * 4 + r;
      bv[mt][r] = (oc < 20) ? bias[oc] : 0.f;
    }
  #pragma unroll
  for (int j = 0; j < 4; ++j) {
    const int phy = j >> 1, phx = j & 1;
    int y = ty0 + 2 * wv + phy, x = tx0 + 2 * nl + phx;
    size_t pxbase = (((size_t)b * P2H + y) * P2W + x) * 24;
    #pragma unroll
    for (int mt = 0; mt < 2; ++mt) {
      if (mt == 1 && q >= 2) continue;                 // record is 24 halves
      floatx4 v = acc[mt][j];
      PK4 pk;
      #pragma unroll
      for (int r = 0; r < 4; ++r) pk.h[r] = (half_t)fmaxf(v[r] + bv[mt][r], 0.f);
      *(uint2*)(X3 + pxbase + mt * 16 + q * 4) = pk.u; // oc 20..23 auto-zero
    }
  }
}

// ---------------- conv4 (20->10, 5x5) + conv5 (10->1, 1x1) + gray residual + relu ----------------
// 2 conv rows/wave: block = 8 rows, window frag[2][6], acc[4], j = phy*2+phx.
// Fused epilogue: q-lanes hold the same pixel (different oc) -> per-lane w5
// partial, shfl_xor(16)+shfl_xor(32) reduce, q==0 adds gray + writes out.
__global__ __launch_bounds__(256, 3) void conv4_mfma(
    const half_t* __restrict__ X3, const half_t* __restrict__ wp,
    const float* __restrict__ bias, const float* __restrict__ w5,
    const float* __restrict__ b5, const float* __restrict__ in,
    float* __restrict__ out)
{
  __shared__ __align__(16) half_t lin[12 * 36 * 24 + 16];   // 20768 B
  const int b = blockIdx.z, ty0 = blockIdx.y * 8, tx0 = blockIdx.x * 32;
  const int tid = threadIdx.x;
  if (tid < 16) lin[12 * 36 * 24 + tid] = (half_t)0.f;
  for (int i = tid; i < 1296; i += 256) {              // 432 px x 3 uint4
    int px = i / 3, part = i - px * 3;
    int row = px / 36, col = px - row * 36;
    int gy = ty0 - 2 + row, gx = tx0 - 2 + col;
    uint4 v = make_uint4(0, 0, 0, 0);
    if (gy >= 0 && gy < P2H && (unsigned)gx < (unsigned)P2W)
      v = *(const uint4*)(X3 + (((size_t)b * P2H + gy) * P2W + gx) * 24 + part * 8);
    *(uint4*)(lin + px * 24 + part * 8) = v;
  }
  __syncthreads();

  const int wv = tid >> 6, ln = tid & 63, q = ln >> 4, nl = ln & 15;
  const int cbase = 2 * nl * 24 + q * 8;
  half8 frag[2][6];
  #pragma unroll
  for (int d = 0; d < 2; ++d) {
    const half_t* rp = lin + (2 * wv + d) * 864 + cbase;
    #pragma unroll
    for (int c = 0; c < 6; ++c) frag[d][c] = *(const half8*)(rp + c * 24);
  }
  const half_t* wA = wp + nl * 32 + q * 8;
  half8 Abuf[2];
  Abuf[0] = *(const half8*)(wA);
  floatx4 acc[4];
  #pragma unroll
  for (int j = 0; j < 4; ++j) acc[j] = (floatx4){0.f, 0.f, 0.f, 0.f};

  #pragma unroll
  for (int ky = 0; ky < 5; ++ky) {
    #pragma unroll
    for (int kx = 0; kx < 5; ++kx) {
      const int tap = ky * 5 + kx;
      if (tap < 24) Abuf[(tap + 1) & 1] = *(const half8*)(wA + (tap + 1) * 512);
      #pragma unroll
      for (int j = 0; j < 4; ++j) {
        const int phy = j >> 1, phx = j & 1;
        half8 B = frag[(phy + ky) & 1][kx + phx];
        acc[j] = __builtin_amdgcn_mfma_f32_16x16x32_f16(Abuf[tap & 1], B, acc[j], 0, 0, 0);
      }
    }
    if (ky < 4) {                                      // slide: row 2wv+ky+2 -> slot ky&1
      const half_t* rp = lin + (2 * wv + ky + 2) * 864 + cbase;
      #pragma unroll
      for (int c = 0; c < 6; ++c) frag[ky & 1][c] = *(const half8*)(rp + c * 24);
    }
  }

  float bv[4], w5v[4];
  #pragma unroll
  for (int r = 0; r < 4; ++r) {
    int oc = q * 4 + r;
    bv[r]  = (oc < 10) ? bias[oc] : 0.f;
    w5v[r] = (oc < 10) ? w5[oc] : 0.f;
  }
  const float b5v = b5[0];
  const float* inb = in + (size_t)b * 3 * (IN_H * IN_W);

  #pragma unroll
  for (int phy = 0; phy < 2; ++phy) {
    const int y = ty0 + 2 * wv + phy;
    const int x0 = tx0 + 2 * nl;                       // phx=0 pixel; phx=1 is x0+1
    float s0 = 0.f, s1 = 0.f;
    #pragma unroll
    for (int r = 0; r < 4; ++r) {
      s0 += w5v[r] * fmaxf(acc[2 * phy + 0][r] + bv[r], 0.f);
      s1 += w5v[r] * fmaxf(acc[2 * phy + 1][r] + bv[r], 0.f);
    }
    s0 += __shfl_xor(s0, 16); s0 += __shfl_xor(s0, 32);
    s1 += __shfl_xor(s1, 16); s1 += __shfl_xor(s1, 32);
    if (q == 0) {
      // gray bilinear: input rows 4y+1,4y+2; cols 4x+1,4x+2 for x = x0, x0+1.
      const size_t cb = (size_t)(4 * y + 1) * IN_W + 4 * x0;
      float g0 = 0.f, g1 = 0.f;
      #pragma unroll
      for (int ch = 0; ch < 3; ++ch) {
        const float coef = (ch == 0) ? 0.299f : ((ch == 1) ? 0.587f : 0.114f);
        const float* qp = inb + (size_t)ch * (IN_H * IN_W);
        float4 a0 = *(const float4*)(qp + cb);
        float4 a1 = *(const float4*)(qp + cb + 4);
        float4 d0 = *(const float4*)(qp + cb + IN_W);
        float4 d1 = *(const float4*)(qp + cb + IN_W + 4);
        g0 += coef * (a0.y + a0.z + d0.y + d0.z);
        g1 += coef * (a1.y + a1.z + d1.y + d1.z);
      }
      float o0 = fmaxf(s0 + b5v + fmaxf(g0 * 0.25f, 0.f), 0.f);
      float o1 = fmaxf(s1 + b5v + fmaxf(g1 * 0.25f, 0.f), 0.f);
      *(float2*)(out + ((size_t)b * P2H + y) * P2W + x0) = make_float2(o0, o1);
    }
  }
}

extern "C" void kernel_launch(void* const* d_in, const int* in_sizes, int n_in,
                              void* d_out, int out_size, void* d_ws, size_t ws_size,
                              hipStream_t stream) {
  const float* input = (const float*)d_in[0];
  const float* w1 = (const float*)d_in[1];  const float* b1 = (const float*)d_in[2];
  const float* w2 = (const float*)d_in[3];  const float* b2 = (const float*)d_in[4];
  const float* w3 = (const float*)d_in[5];  const float* b3 = (const float*)d_in[6];
  const float* w4 = (const float*)d_in[7];  const float* b4 = (const float*)d_in[8];
  const float* w5 = (const float*)d_in[9];  const float* b5 = (const float*)d_in[10];
  float* out = (float*)d_out;
  char* ws = (char*)d_ws;

  half_t* P2h = (half_t*)(ws + OFF_P2);
  half_t* P1h = (half_t*)(ws + OFF_P1);
  half_t* X3h = (half_t*)(ws + OFF_X3);
  half_t* wp2 = (half_t*)(ws + OFF_W2);
  half_t* wp3 = (half_t*)(ws + OFF_W3);
  half_t* wp4 = (half_t*)(ws + OFF_W4);
  half_t* wp1 = (half_t*)(ws + OFF_W1);

  pack_weights<<<432, 256, 0, stream>>>(w2, w3, w4, w1, wp2, wp3, wp4, wp1);
  conv1_mfma<<<dim3(32, 24, 8), 256, 0, stream>>>(input, wp1, b1, P1h);
  conv2_mfma<<<dim3(16, 48, 8), 256, 0, stream>>>(P1h, wp2, b2, P2h);
  conv3_mfma<<<dim3(8, 24, 8), 256, 0, stream>>>(P2h, wp3, b3, X3h);
  conv4_mfma<<<dim3(8, 24, 8), 256, 0, stream>>>(X3h, wp4, b4, w5, b5, input, out);
}

// Round 7
// 405.081 us; speedup vs baseline: 1.1653x; 1.0216x over previous
//
#include <hip/hip_runtime.h>

// Res_MCNN_branch2 on gfx950 — all convs f16 MFMA implicit-GEMM (16x16x32).
// R16 = R13 (proven 379 µs) with conv2/conv4 converted to DIRECT-GLOBAL
// B-fragment reads: no LDS, no staging loop, no __syncthreads. Window
// frag[4][6] slides read 16B-aligned half8 straight from P1/X3 (records are
// 48B; q*16 sub-offset keeps alignment; a wave spans ~800 contiguous bytes
// per load -> L1/L2-friendly). Interior blocks unguarded; edge blocks
// per-frag bounds -> zero (identical numerics: all spill/pad K-slots have
// zero weights; tensor tail abuts finite weight region).
// WHY: R14/R15 falsified occupancy as conv2's limiter (44% occ made it
// SLOWER, MfmaUtil 37%); the cost was the stage->barrier->compute serial
// structure itself. This removes it.
// Failure ledger: R11 gload_lds DMA (22x FETCH), R12 multi-tile reg staging
// (L2 thrash), R14 g-split (spill), R15 2-row waves (per-MFMA overhead x2).
// Layouts: P1 NHWC24, P2 NHWC56, X3 NHWC24. conv4+conv5 fused (R13).

typedef _Float16 half_t;
typedef _Float16 half8 __attribute__((ext_vector_type(8)));
typedef float floatx4 __attribute__((ext_vector_type(4)));

#define IN_H 768
#define IN_W 1024
#define P1H 384
#define P1W 512
#define P2H 192
#define P2W 256

// workspace offsets (bytes)
#define OFF_P2 0ULL                 // f16 [8][192][256][56] = 44,040,192
#define OFF_P1 44040192ULL          // f16 [8][384][512][24] = 75,497,472
#define OFF_X3 44040192ULL          // reuse P1 region after conv2
#define OFF_W2 119537664ULL         // f16 [25][48][32] = 76,800 el  (abuts P1/X3 end: finite spill target)
#define OFF_W3 119691264ULL         // f16 [25][32][64] = 102,400 el
#define OFF_W4 119896064ULL         // f16 [25][16][32] = 25,600 el
#define OFF_W1 119947264ULL         // f16 [7][32][32]  = 7,168 el

union PK4 { half_t h[4]; uint2 u; };
union U8 { half8 v; uint2 u[2]; };

__device__ __forceinline__ half8 h8zero() {
  half8 z;
  #pragma unroll
  for (int i = 0; i < 8; ++i) z[i] = (half_t)0.f;
  return z;
}

// ---------------- weight pre-pack (fp32 OIHW -> f16 packed, linear) ----------------
__global__ __launch_bounds__(256) void pack_weights(
    const float* __restrict__ w2, const float* __restrict__ w3,
    const float* __restrict__ w4, const float* __restrict__ w1,
    half_t* __restrict__ wp2, half_t* __restrict__ wp3, half_t* __restrict__ wp4,
    half_t* __restrict__ wp1)
{
  int t = blockIdx.x * 256 + threadIdx.x;
  if (t < 38400) {                       // conv2: [25][48][32]
    int tap = t / 1536, r = t % 1536, oc = r >> 5, c = r & 31;
    float v = (oc < 40 && c < 20) ? w2[(oc * 20 + c) * 25 + tap] : 0.f;
    wp2[t] = (half_t)v;
  } else if (t < 89600) {                // conv3: [25][32][64]
    int u = t - 38400;
    int tap = u / 2048, r = u % 2048, oc = r >> 6, c = r & 63;
    float v = (oc < 20 && c < 40) ? w3[(oc * 40 + c) * 25 + tap] : 0.f;
    wp3[u] = (half_t)v;
  } else if (t < 102400) {               // conv4: [25][16][32]
    int u = t - 89600;
    int tap = u / 512, r = u % 512, oc = r >> 5, c = r & 31;
    float v = (oc < 10 && c < 20) ? w4[(oc * 20 + c) * 25 + tap] : 0.f;
    wp4[u] = (half_t)v;
  } else if (t < 109568) {               // conv1: [7][32][32], k = kx*4+c
    int u = t - 102400;
    int ky = u / 1024, r = u % 1024, oc = r >> 5, k = r & 31;
    int kx = k >> 2, c = k & 3;
    float v = (oc < 20 && c < 3 && kx < 7) ? w1[((oc * 3 + c) * 7 + ky) * 7 + kx] : 0.f;
    wp1[u] = (half_t)v;
  }
}

// ---------------- conv1 (3->20, 7x7, pad 3) MFMA + relu + pool -> P1 f16 NHWC24 ----------------
// 32-row tile, stage once (38x40 region, origin tx0-4 for float4 alignment),
// two K-loop passes p=0,1. Interior blocks: unguarded float4 staging.
__global__ __launch_bounds__(256) void conv1_mfma(
    const float* __restrict__ in, const half_t* __restrict__ wp,
    const float* __restrict__ bias, half_t* __restrict__ P1)
{
  __shared__ __align__(16) half_t ltile[38 * 40 * 4];   // 12160 B, row stride 40 px
  const int b = blockIdx.z, ty0 = blockIdx.y * 32, tx0 = blockIdx.x * 32;
  const int tid = threadIdx.x;
  const int HW1 = IN_H * IN_W;

  const float* p0 = in + (size_t)b * 3 * HW1;
  const bool interior = (blockIdx.x >= 1) && (blockIdx.x <= 30) &&
                        (blockIdx.y >= 1) && (blockIdx.y <= 22);
  if (interior) {
    for (int i = tid; i < 380; i += 256) {              // 38 rows x 10 float4
      int r = i / 10, c4 = i - r * 10;
      const float* pr = p0 + (size_t)(ty0 - 3 + r) * IN_W + (tx0 - 4 + 4 * c4);
      float4 v0 = *(const float4*)(pr);
      float4 v1 = *(const float4*)(pr + HW1);
      float4 v2 = *(const float4*)(pr + 2 * HW1);
      PK4 a0, a1, a2, a3;
      a0.h[0] = (half_t)v0.x; a0.h[1] = (half_t)v1.x; a0.h[2] = (half_t)v2.x; a0.h[3] = (half_t)0.f;
      a1.h[0] = (half_t)v0.y; a1.h[1] = (half_t)v1.y; a1.h[2] = (half_t)v2.y; a1.h[3] = (half_t)0.f;
      a2.h[0] = (half_t)v0.z; a2.h[1] = (half_t)v1.z; a2.h[2] = (half_t)v2.z; a2.h[3] = (half_t)0.f;
      a3.h[0] = (half_t)v0.w; a3.h[1] = (half_t)v1.w; a3.h[2] = (half_t)v2.w; a3.h[3] = (half_t)0.f;
      uint4* dst = (uint4*)(ltile + (r * 40 + 4 * c4) * 4);
      dst[0] = make_uint4(a0.u.x, a0.u.y, a1.u.x, a1.u.y);
      dst[1] = make_uint4(a2.u.x, a2.u.y, a3.u.x, a3.u.y);
    }
  } else {
    for (int i = tid; i < 1520; i += 256) {             // 38 rows x 40 cols, guarded
      int r = i / 40, c = i - r * 40;
      int gy = ty0 - 3 + r, gx = tx0 - 4 + c;
      float v0 = 0.f, v1 = 0.f, v2 = 0.f;
      if (gy >= 0 && gy < IN_H && (unsigned)gx < (unsigned)IN_W) {
        size_t o = (size_t)gy * IN_W + gx;
        v0 = p0[o];
        v1 = p0[o + HW1];
        v2 = p0[o + 2 * HW1];
      }
      PK4 pk;
      pk.h[0] = (half_t)v0; pk.h[1] = (half_t)v1;
      pk.h[2] = (half_t)v2; pk.h[3] = (half_t)0.f;
      *(uint2*)(ltile + (r * 40 + c) * 4) = pk.u;
    }
  }
  __syncthreads();

  const int wv = tid >> 6, ln = tid & 63, q = ln >> 4, nl = ln & 15;
  const int cbase = (2 * nl + 2 * q + 1) * 4;           // +1: tile origin tx0-4
  const half_t* wA = wp + nl * 32 + q * 8;

  floatx4 bv[2];
  #pragma unroll
  for (int mt = 0; mt < 2; ++mt)
    #pragma unroll
    for (int r = 0; r < 4; ++r) {
      int oc = mt * 16 + q * 4 + r;
      bv[mt][r] = (oc < 20) ? bias[oc] : 0.f;
    }
  const int pc = (tx0 >> 1) + nl;

  #pragma unroll
  for (int p = 0; p < 2; ++p) {
    const int rbase = p * 16 + 4 * wv;            // ltile row of this pass/wave
    U8 frag[4][2];
    #pragma unroll
    for (int d = 0; d < 4; ++d) {
      const half_t* rp = ltile + (rbase + d) * 160 + cbase;
      #pragma unroll
      for (int phx = 0; phx < 2; ++phx) {
        frag[d][phx].u[0] = *(const uint2*)(rp + phx * 4);
        frag[d][phx].u[1] = *(const uint2*)(rp + phx * 4 + 4);
      }
    }
    half8 Abuf[2][2];
    Abuf[0][0] = *(const half8*)(wA);
    Abuf[0][1] = *(const half8*)(wA + 512);
    floatx4 acc[2][8];
    #pragma unroll
    for (int mt = 0; mt < 2; ++mt)
      #pragma unroll
      for (int j = 0; j < 8; ++j) acc[mt][j] = (floatx4){0.f, 0.f, 0.f, 0.f};

    #pragma unroll
    for (int ky = 0; ky < 7; ++ky) {
      if (ky < 6) {
        Abuf[(ky + 1) & 1][0] = *(const half8*)(wA + (ky + 1) * 1024);
        Abuf[(ky + 1) & 1][1] = *(const half8*)(wA + (ky + 1) * 1024 + 512);
      }
      #pragma unroll
      for (int j = 0; j < 8; ++j) {
        const int g = j >> 2, ph = j & 3, phy = ph >> 1, phx = ph & 1;
        half8 B = frag[(2 * g + phy + ky) & 3][phx].v;
        acc[0][j] = __builtin_amdgcn_mfma_f32_16x16x32_f16(Abuf[ky & 1][0], B, acc[0][j], 0, 0, 0);
        acc[1][j] = __builtin_amdgcn_mfma_f32_16x16x32_f16(Abuf[ky & 1][1], B, acc[1][j], 0, 0, 0);
      }
      if (ky < 6) {                               // slide: ltile row rbase+ky+4 -> slot ky&3
        const half_t* rp = ltile + (rbase + ky + 4) * 160 + cbase;
        #pragma unroll
        for (int phx = 0; phx < 2; ++phx) {
          frag[ky & 3][phx].u[0] = *(const uint2*)(rp + phx * 4);
          frag[ky & 3][phx].u[1] = *(const uint2*)(rp + phx * 4 + 4);
        }
      }
    }

    const int pr0 = (ty0 >> 1) + 8 * p + 2 * wv;
    #pragma unroll
    for (int g = 0; g < 2; ++g) {
      size_t pxbase = (((size_t)b * P1H + pr0 + g) * P1W + pc) * 24;
      PK4 pk0;
      #pragma unroll
      for (int r = 0; r < 4; ++r) {
        float x = fmaxf(fmaxf(acc[0][g * 4 + 0][r], acc[0][g * 4 + 1][r]),
                        fmaxf(acc[0][g * 4 + 2][r], acc[0][g * 4 + 3][r]));
        pk0.h[r] = (half_t)fmaxf(x + bv[0][r], 0.f);
      }
      *(uint2*)(P1 + pxbase + q * 4) = pk0.u;           // oc 0..15
      if (q < 2) {                                      // oc 16..19 real, 20..23 = 0
        PK4 pk1;
        #pragma unroll
        for (int r = 0; r < 4; ++r) {
          float x = fmaxf(fmaxf(acc[1][g * 4 + 0][r], acc[1][g * 4 + 1][r]),
                          fmaxf(acc[1][g * 4 + 2][r], acc[1][g * 4 + 3][r]));
          pk1.h[r] = (half_t)fmaxf(x + bv[1][r], 0.f);
        }
        *(uint2*)(P1 + pxbase + 16 + q * 4) = pk1.u;
      }
    }
  }
}

// ---------------- conv2 (20->40, 5x5) MFMA + relu + pool -> P2 f16 NHWC56 ----------------
// Direct-global B-frags: no LDS, no barrier. Window frag[4][6] slides read
// half8 straight from P1 (16B-aligned). Interior blocks unguarded; edge
// blocks per-frag bounds -> zero. q=3 frag spills into next record / weight
// region: zero weights there, finite bytes -> exact same results as staged.
__global__ __launch_bounds__(256, 2) void conv2_mfma(
    const half_t* __restrict__ P1, const half_t* __restrict__ wp,
    const float* __restrict__ bias, half_t* __restrict__ P2)
{
  const int b = blockIdx.z, ty0 = blockIdx.y * 16, tx0 = blockIdx.x * 32;
  const int tid = threadIdx.x;
  const int wv = tid >> 6, ln = tid & 63, q = ln >> 4, nl = ln & 15;

  const bool interior = (blockIdx.x >= 1) && (blockIdx.x <= 14) &&
                        (blockIdx.y >= 1) && (blockIdx.y <= 22);
  const int RS = P1W * 24;                             // row stride, halves
  // per-lane base at tile row rr=0 (gy = ty0-2), col 2nl (gx = tx0-2+2nl)
  const half_t* gb = P1 + (((size_t)b * P1H + (ty0 - 2)) * P1W + (tx0 - 2 + 2 * nl)) * 24 + q * 8;

  half8 frag[4][6];
  if (interior) {
    #pragma unroll
    for (int d = 0; d < 4; ++d) {
      const half_t* rp = gb + (4 * wv + d) * RS;
      #pragma unroll
      for (int c = 0; c < 6; ++c) frag[d][c] = *(const half8*)(rp + c * 24);
    }
  } else {
    #pragma unroll
    for (int d = 0; d < 4; ++d) {
      const int gy = ty0 - 2 + 4 * wv + d;
      #pragma unroll
      for (int c = 0; c < 6; ++c) {
        const int gx = tx0 - 2 + 2 * nl + c;
        frag[d][c] = ((unsigned)gy < (unsigned)P1H && (unsigned)gx < (unsigned)P1W)
            ? *(const half8*)(P1 + (((size_t)b * P1H + gy) * P1W + gx) * 24 + q * 8)
            : h8zero();
      }
    }
  }

  const half_t* wA = wp + nl * 32 + q * 8;
  half8 Abuf[2][3];
  #pragma unroll
  for (int mt = 0; mt < 3; ++mt) Abuf[0][mt] = *(const half8*)(wA + mt * 512);
  floatx4 acc[3][8];
  #pragma unroll
  for (int mt = 0; mt < 3; ++mt)
    #pragma unroll
    for (int j = 0; j < 8; ++j) acc[mt][j] = (floatx4){0.f, 0.f, 0.f, 0.f};

  #pragma unroll
  for (int ky = 0; ky < 5; ++ky) {
    #pragma unroll
    for (int kx = 0; kx < 5; ++kx) {
      const int tap = ky * 5 + kx;
      if (tap < 24) {
        #pragma unroll
        for (int mt = 0; mt < 3; ++mt)
          Abuf[(tap + 1) & 1][mt] = *(const half8*)(wA + (tap + 1) * 1536 + mt * 512);
      }
      #pragma unroll
      for (int j = 0; j < 8; ++j) {
        const int g = j >> 2, ph = j & 3, phy = ph >> 1, phx = ph & 1;
        half8 B = frag[(2 * g + phy + ky) & 3][kx + phx];
        acc[0][j] = __builtin_amdgcn_mfma_f32_16x16x32_f16(Abuf[tap & 1][0], B, acc[0][j], 0, 0, 0);
        acc[1][j] = __builtin_amdgcn_mfma_f32_16x16x32_f16(Abuf[tap & 1][1], B, acc[1][j], 0, 0, 0);
        acc[2][j] = __builtin_amdgcn_mfma_f32_16x16x32_f16(Abuf[tap & 1][2], B, acc[2][j], 0, 0, 0);
      }
    }
    if (ky < 4) {                                      // slide: tile row 4wv+ky+4 -> slot ky&3
      const int rr = 4 * wv + ky + 4;
      if (interior) {
        const half_t* rp = gb + rr * RS;
        #pragma unroll
        for (int c = 0; c < 6; ++c) frag[ky & 3][c] = *(const half8*)(rp + c * 24);
      } else {
        const int gy = ty0 - 2 + rr;
        #pragma unroll
        for (int c = 0; c < 6; ++c) {
          const int gx = tx0 - 2 + 2 * nl + c;
          frag[ky & 3][c] = ((unsigned)gy < (unsigned)P1H && (unsigned)gx < (unsigned)P1W)
              ? *(const half8*)(P1 + (((size_t)b * P1H + gy) * P1W + gx) * 24 + q * 8)
              : h8zero();
        }
      }
    }
  }

  floatx4 bv[3];
  #pragma unroll
  for (int mt = 0; mt < 3; ++mt)
    #pragma unroll
    for (int r = 0; r < 4; ++r) {
      int oc = mt * 16 + q * 4 + r;
      bv[mt][r] = (oc < 40) ? bias[oc] : 0.f;
    }
  const int pr0 = (ty0 >> 1) + 2 * wv;
  const int pc = (tx0 >> 1) + nl;
  #pragma unroll
  for (int g = 0; g < 2; ++g) {
    size_t pxbase = (((size_t)b * P2H + pr0 + g) * P2W + pc) * 56;
    #pragma unroll
    for (int mt = 0; mt < 3; ++mt) {
      PK4 pk;
      #pragma unroll
      for (int r = 0; r < 4; ++r) {
        float x = fmaxf(fmaxf(acc[mt][g * 4 + 0][r], acc[mt][g * 4 + 1][r]),
                        fmaxf(acc[mt][g * 4 + 2][r], acc[mt][g * 4 + 3][r]));
        pk.h[r] = (half_t)fmaxf(x + bv[mt][r], 0.f);   // oc 40..47: 0+0 -> 0 pad
      }
      *(uint2*)(P2 + pxbase + mt * 16 + q * 4) = pk.u;
    }
    if (q == 0)
      *(uint4*)(P2 + pxbase + 48) = make_uint4(0, 0, 0, 0);  // halves 48..55 = 0
  }
}

// ---------------- conv3 (40->20, 5x5) MFMA + relu -> X3 f16 NHWC24 ----------------
// P2 records 56 halves (40 real + 16 zero). Window frag[2][6][2cb] + A prefetch.
__global__ __launch_bounds__(256, 2) void conv3_mfma(
    const half_t* __restrict__ P2, const half_t* __restrict__ wp,
    const float* __restrict__ bias, half_t* __restrict__ X3)
{
  __shared__ __align__(16) half_t lin[12 * 36 * 56 + 16];   // 48416 B
  const int b = blockIdx.z, ty0 = blockIdx.y * 8, tx0 = blockIdx.x * 32;
  const int tid = threadIdx.x;
  if (tid < 16) lin[12 * 36 * 56 + tid] = (half_t)0.f;
  for (int i = tid; i < 3024; i += 256) {              // 432 px x 7 uint4
    int px = i / 7, part = i - px * 7;
    int row = px / 36, col = px - row * 36;
    int gy = ty0 - 2 + row, gx = tx0 - 2 + col;
    uint4 v = make_uint4(0, 0, 0, 0);
    if (gy >= 0 && gy < P2H && (unsigned)gx < (unsigned)P2W)
      v = *(const uint4*)(P2 + (((size_t)b * P2H + gy) * P2W + gx) * 56 + part * 8);
    *(uint4*)(lin + px * 56 + part * 8) = v;
  }
  __syncthreads();

  const int wv = tid >> 6, ln = tid & 63, q = ln >> 4, nl = ln & 15;
  const int cbase = 2 * nl * 56 + q * 8;               // + row*2016 + c*56 + cb*32
  half8 frag[2][6][2];
  #pragma unroll
  for (int c = 0; c < 6; ++c)
    #pragma unroll
    for (int cb = 0; cb < 2; ++cb) {
      frag[0][c][cb] = *(const half8*)(lin + (2 * wv + 0) * 2016 + cbase + c * 56 + cb * 32);
      frag[1][c][cb] = *(const half8*)(lin + (2 * wv + 1) * 2016 + cbase + c * 56 + cb * 32);
    }
  const half_t* wA = wp + nl * 64 + q * 8;
  half8 Abuf[2][2][2];                                 // [parity][mt][cb]
  #pragma unroll
  for (int mt = 0; mt < 2; ++mt)
    #pragma unroll
    for (int cb = 0; cb < 2; ++cb)
      Abuf[0][mt][cb] = *(const half8*)(wA + mt * 1024 + cb * 32);
  floatx4 acc[2][4];
  #pragma unroll
  for (int mt = 0; mt < 2; ++mt)
    #pragma unroll
    for (int j = 0; j < 4; ++j) acc[mt][j] = (floatx4){0.f, 0.f, 0.f, 0.f};

  #pragma unroll
  for (int ky = 0; ky < 5; ++ky) {
    #pragma unroll
    for (int kx = 0; kx < 5; ++kx) {
      const int tap = ky * 5 + kx;
      if (tap < 24) {
        #pragma unroll
        for (int mt = 0; mt < 2; ++mt)
          #pragma unroll
          for (int cb = 0; cb < 2; ++cb)
            Abuf[(tap + 1) & 1][mt][cb] =
                *(const half8*)(wA + (tap + 1) * 2048 + mt * 1024 + cb * 32);
      }
      #pragma unroll
      for (int cb = 0; cb < 2; ++cb)
        #pragma unroll
        for (int j = 0; j < 4; ++j) {
          const int phy = j >> 1, phx = j & 1;
          half8 B = frag[(ky + phy) & 1][kx + phx][cb];
          acc[0][j] = __builtin_amdgcn_mfma_f32_16x16x32_f16(Abuf[tap & 1][0][cb], B, acc[0][j], 0, 0, 0);
          acc[1][j] = __builtin_amdgcn_mfma_f32_16x16x32_f16(Abuf[tap & 1][1][cb], B, acc[1][j], 0, 0, 0);
        }
    }
    if (ky < 4) {
      const half_t* rp = lin + (2 * wv + ky + 2) * 2016 + cbase;
      #pragma unroll
      for (int c = 0; c < 6; ++c)
        #pragma unroll
        for (int cb = 0; cb < 2; ++cb)
          frag[ky & 1][c][cb] = *(const half8*)(rp + c * 56 + cb * 32);
    }
  }

  floatx4 bv[2];
  #pragma unroll
  for (int mt = 0; mt < 2; ++mt)
    #pragma unroll
    for (int r = 0; r < 4; ++r) {
      int oc = mt * 16 + q * 4 + r;
      bv[mt][r] = (oc < 20) ? bias[oc] : 0.f;
    }
  #pragma unroll
  for (int j = 0; j < 4; ++j) {
    const int phy = j >> 1, phx = j & 1;
    int y = ty0 + 2 * wv + phy, x = tx0 + 2 * nl + phx;
    size_t pxbase = (((size_t)b * P2H + y) * P2W + x) * 24;
    #pragma unroll
    for (int mt = 0; mt < 2; ++mt) {
      if (mt == 1 && q >= 2) continue;                 // record is 24 halves
      floatx4 v = acc[mt][j];
      PK4 pk;
      #pragma unroll
      for (int r = 0; r < 4; ++r) pk.h[r] = (half_t)fmaxf(v[r] + bv[mt][r], 0.f);
      *(uint2*)(X3 + pxbase + mt * 16 + q * 4) = pk.u; // oc 20..23 auto-zero
    }
  }
}

// ---------------- conv4 (20->10, 5x5) + conv5 (10->1, 1x1) + gray residual + relu ----------------
// Direct-global B-frags (as conv2): no LDS, no barrier. X3 records 24 halves.
// Fused epilogue: q-lanes hold the same pixel (different oc) -> per-lane w5
// partial, shfl_xor(16)+shfl_xor(32) reduce, q==0 adds gray + writes out.
__global__ __launch_bounds__(256, 2) void conv4_mfma(
    const half_t* __restrict__ X3, const half_t* __restrict__ wp,
    const float* __restrict__ bias, const float* __restrict__ w5,
    const float* __restrict__ b5, const float* __restrict__ in,
    float* __restrict__ out)
{
  const int b = blockIdx.z, ty0 = blockIdx.y * 16, tx0 = blockIdx.x * 32;
  const int tid = threadIdx.x;
  const int wv = tid >> 6, ln = tid & 63, q = ln >> 4, nl = ln & 15;

  const bool interior = (blockIdx.x >= 1) && (blockIdx.x <= 6) &&
                        (blockIdx.y >= 1) && (blockIdx.y <= 10);
  const int RS = P2W * 24;                             // row stride, halves
  const half_t* gb = X3 + (((size_t)b * P2H + (ty0 - 2)) * P2W + (tx0 - 2 + 2 * nl)) * 24 + q * 8;

  half8 frag[4][6];
  if (interior) {
    #pragma unroll
    for (int d = 0; d < 4; ++d) {
      const half_t* rp = gb + (4 * wv + d) * RS;
      #pragma unroll
      for (int c = 0; c < 6; ++c) frag[d][c] = *(const half8*)(rp + c * 24);
    }
  } else {
    #pragma unroll
    for (int d = 0; d < 4; ++d) {
      const int gy = ty0 - 2 + 4 * wv + d;
      #pragma unroll
      for (int c = 0; c < 6; ++c) {
        const int gx = tx0 - 2 + 2 * nl + c;
        frag[d][c] = ((unsigned)gy < (unsigned)P2H && (unsigned)gx < (unsigned)P2W)
            ? *(const half8*)(X3 + (((size_t)b * P2H + gy) * P2W + gx) * 24 + q * 8)
            : h8zero();
      }
    }
  }

  const half_t* wA = wp + nl * 32 + q * 8;
  half8 Abuf[2];
  Abuf[0] = *(const half8*)(wA);
  floatx4 acc[8];
  #pragma unroll
  for (int j = 0; j < 8; ++j) acc[j] = (floatx4){0.f, 0.f, 0.f, 0.f};

  #pragma unroll
  for (int ky = 0; ky < 5; ++ky) {
    #pragma unroll
    for (int kx = 0; kx < 5; ++kx) {
      const int tap = ky * 5 + kx;
      if (tap < 24) Abuf[(tap + 1) & 1] = *(const half8*)(wA + (tap + 1) * 512);
      #pragma unroll
      for (int j = 0; j < 8; ++j) {
        const int g = j >> 2, ph = j & 3, phy = ph >> 1, phx = ph & 1;
        half8 B = frag[(2 * g + phy + ky) & 3][kx + phx];
        acc[j] = __builtin_amdgcn_mfma_f32_16x16x32_f16(Abuf[tap & 1], B, acc[j], 0, 0, 0);
      }
    }
    if (ky < 4) {                                      // slide: tile row 4wv+ky+4 -> slot ky&3
      const int rr = 4 * wv + ky + 4;
      if (interior) {
        const half_t* rp = gb + rr * RS;
        #pragma unroll
        for (int c = 0; c < 6; ++c) frag[ky & 3][c] = *(const half8*)(rp + c * 24);
      } else {
        const int gy = ty0 - 2 + rr;
        #pragma unroll
        for (int c = 0; c < 6; ++c) {
          const int gx = tx0 - 2 + 2 * nl + c;
          frag[ky & 3][c] = ((unsigned)gy < (unsigned)P2H && (unsigned)gx < (unsigned)P2W)
              ? *(const half8*)(X3 + (((size_t)b * P2H + gy) * P2W + gx) * 24 + q * 8)
              : h8zero();
        }
      }
    }
  }

  float bv[4], w5v[4];
  #pragma unroll
  for (int r = 0; r < 4; ++r) {
    int oc = q * 4 + r;
    bv[r]  = (oc < 10) ? bias[oc] : 0.f;
    w5v[r] = (oc < 10) ? w5[oc] : 0.f;
  }
  const float b5v = b5[0];
  const float* inb = in + (size_t)b * 3 * (IN_H * IN_W);

  #pragma unroll
  for (int g = 0; g < 2; ++g)
    #pragma unroll
    for (int phy = 0; phy < 2; ++phy) {
      const int y = ty0 + 4 * wv + 2 * g + phy;
      const int x0 = tx0 + 2 * nl;                     // phx=0 pixel; phx=1 is x0+1
      float s0 = 0.f, s1 = 0.f;
      #pragma unroll
      for (int r = 0; r < 4; ++r) {
        s0 += w5v[r] * fmaxf(acc[g * 4 + 2 * phy + 0][r] + bv[r], 0.f);
        s1 += w5v[r] * fmaxf(acc[g * 4 + 2 * phy + 1][r] + bv[r], 0.f);
      }
      s0 += __shfl_xor(s0, 16); s0 += __shfl_xor(s0, 32);
      s1 += __shfl_xor(s1, 16); s1 += __shfl_xor(s1, 32);
      if (q == 0) {
        // gray bilinear: input rows 4y+1,4y+2; cols 4x+1,4x+2 for x = x0, x0+1.
        const size_t cb = (size_t)(4 * y + 1) * IN_W + 4 * x0;
        float g0 = 0.f, g1 = 0.f;
        #pragma unroll
        for (int ch = 0; ch < 3; ++ch) {
          const float coef = (ch == 0) ? 0.299f : ((ch == 1) ? 0.587f : 0.114f);
          const float* qp = inb + (size_t)ch * (IN_H * IN_W);
          float4 a0 = *(const float4*)(qp + cb);
          float4 a1 = *(const float4*)(qp + cb + 4);
          float4 d0 = *(const float4*)(qp + cb + IN_W);
          float4 d1 = *(const float4*)(qp + cb + IN_W + 4);
          g0 += coef * (a0.y + a0.z + d0.y + d0.z);
          g1 += coef * (a1.y + a1.z + d1.y + d1.z);
        }
        float o0 = fmaxf(s0 + b5v + fmaxf(g0 * 0.25f, 0.f), 0.f);
        float o1 = fmaxf(s1 + b5v + fmaxf(g1 * 0.25f, 0.f), 0.f);
        *(float2*)(out + ((size_t)b * P2H + y) * P2W + x0) = make_float2(o0, o1);
      }
    }
}

extern "C" void kernel_launch(void* const* d_in, const int* in_sizes, int n_in,
                              void* d_out, int out_size, void* d_ws, size_t ws_size,
                              hipStream_t stream) {
  const float* input = (const float*)d_in[0];
  const float* w1 = (const float*)d_in[1];  const float* b1 = (const float*)d_in[2];
  const float* w2 = (const float*)d_in[3];  const float* b2 = (const float*)d_in[4];
  const float* w3 = (const float*)d_in[5];  const float* b3 = (const float*)d_in[6];
  const float* w4 = (const float*)d_in[7];  const float* b4 = (const float*)d_in[8];
  const float* w5 = (const float*)d_in[9];  const float* b5 = (const float*)d_in[10];
  float* out = (float*)d_out;
  char* ws = (char*)d_ws;

  half_t* P2h = (half_t*)(ws + OFF_P2);
  half_t* P1h = (half_t*)(ws + OFF_P1);
  half_t* X3h = (half_t*)(ws + OFF_X3);
  half_t* wp2 = (half_t*)(ws + OFF_W2);
  half_t* wp3 = (half_t*)(ws + OFF_W3);
  half_t* wp4 = (half_t*)(ws + OFF_W4);
  half_t* wp1 = (half_t*)(ws + OFF_W1);

  pack_weights<<<432, 256, 0, stream>>>(w2, w3, w4, w1, wp2, wp3, wp4, wp1);
  conv1_mfma<<<dim3(32, 24, 8), 256, 0, stream>>>(input, wp1, b1, P1h);
  conv2_mfma<<<dim3(16, 24, 8), 256, 0, stream>>>(P1h, wp2, b2, P2h);
  conv3_mfma<<<dim3(8, 24, 8), 256, 0, stream>>>(P2h, wp3, b3, X3h);
  conv4_mfma<<<dim3(8, 12, 8), 256, 0, stream>>>(X3h, wp4, b4, w5, b5, input, out);
}

// Round 8
// 365.233 us; speedup vs baseline: 1.2925x; 1.1091x over previous
//
#include <hip/hip_runtime.h>

// Res_MCNN_branch2 on gfx950 — all convs f16 MFMA implicit-GEMM (16x16x32).
// R17 = R13 (proven 379 µs) + K-FOLDED conv2/conv4: since P1/X3 are NHWC24
// with pixels contiguous in x, the 5 kx taps of one ky form ONE contiguous
// 120-half span -> 4 K=32 steps (78% util) instead of 5 taps (62.5%) ->
// 20% fewer MFMAs (600->480/wave). Weights repacked [ky][kk][rows][32] with
// slot o -> (pixel o/24, ch o%24), zero-padded. All reads stay 16B-aligned
// (record 48B, step 64B, q*16B). The x-window frag array disappears (-96
// live regs; B = transient load feeding 3 MFMAs). R13's MFMA-busy was ~88%
// of its padded issue floor — cutting MFMA count is the remaining lever.
// Failure ledger (all conv2, all reverted): R11 gload_lds DMA (22x FETCH),
// R12 multi-tile reg-staging (L2 thrash), R14 g-split (spill), R15 2-row
// waves (2x per-MFMA overhead), R16 direct-global (spill, WRITE 43->128MB).
// Layouts: P1 NHWC24, P2 NHWC56, X3 NHWC24. conv4+conv5 fused (R13).

typedef _Float16 half_t;
typedef _Float16 half8 __attribute__((ext_vector_type(8)));
typedef float floatx4 __attribute__((ext_vector_type(4)));

#define IN_H 768
#define IN_W 1024
#define P1H 384
#define P1W 512
#define P2H 192
#define P2W 256

// workspace offsets (bytes)
#define OFF_P2 0ULL                 // f16 [8][192][256][56] = 44,040,192
#define OFF_P1 44040192ULL          // f16 [8][384][512][24] = 75,497,472
#define OFF_X3 44040192ULL          // reuse P1 region after conv2
#define OFF_W2 119537664ULL         // f16 [5][4][48][32] = 30,720 el (K-folded)
#define OFF_W3 119599104ULL         // f16 [25][32][64]   = 102,400 el
#define OFF_W4 119803904ULL         // f16 [5][4][16][32] = 10,240 el (K-folded)
#define OFF_W1 119824384ULL         // f16 [7][32][32]    = 7,168 el

union PK4 { half_t h[4]; uint2 u; };
union U8 { half8 v; uint2 u[2]; };

// ---------------- weight pre-pack (fp32 OIHW -> f16 packed, linear) ----------------
__global__ __launch_bounds__(256) void pack_weights(
    const float* __restrict__ w2, const float* __restrict__ w3,
    const float* __restrict__ w4, const float* __restrict__ w1,
    half_t* __restrict__ wp2, half_t* __restrict__ wp3, half_t* __restrict__ wp4,
    half_t* __restrict__ wp1)
{
  int t = blockIdx.x * 256 + threadIdx.x;
  if (t < 30720) {                       // conv2 K-folded: [5 ky][4 kk][48 oc][32 k]
    int ky = t / 6144, r = t % 6144;
    int kk = r / 1536, r2 = r % 1536, oc = r2 >> 5, k = r2 & 31;
    int o = kk * 32 + k, p = o / 24, c = o % 24;   // pixel offset p (=kx), channel c
    float v = (oc < 40 && c < 20 && p < 5) ? w2[(oc * 20 + c) * 25 + ky * 5 + p] : 0.f;
    wp2[t] = (half_t)v;
  } else if (t < 81920) {                // conv3: [25][32][64] (unchanged)
    int u = t - 30720;
    int tap = u / 2048, r = u % 2048, oc = r >> 6, c = r & 63;
    float v = (oc < 20 && c < 40) ? w3[(oc * 40 + c) * 25 + tap] : 0.f;
    wp3[u] = (half_t)v;
  } else if (t < 92160) {                // conv4 K-folded: [5 ky][4 kk][16 oc][32 k]
    int u = t - 81920;
    int ky = u / 2048, r = u % 2048;
    int kk = r / 512, r2 = r % 512, oc = r2 >> 5, k = r2 & 31;
    int o = kk * 32 + k, p = o / 24, c = o % 24;
    float v = (oc < 10 && c < 20 && p < 5) ? w4[(oc * 20 + c) * 25 + ky * 5 + p] : 0.f;
    wp4[u] = (half_t)v;
  } else if (t < 99328) {                // conv1: [7][32][32], k = kx*4+c (unchanged)
    int u = t - 92160;
    int ky = u / 1024, r = u % 1024, oc = r >> 5, k = r & 31;
    int kx = k >> 2, c = k & 3;
    float v = (oc < 20 && c < 3 && kx < 7) ? w1[((oc * 3 + c) * 7 + ky) * 7 + kx] : 0.f;
    wp1[u] = (half_t)v;
  }
}

// ---------------- conv1 (3->20, 7x7, pad 3) MFMA + relu + pool -> P1 f16 NHWC24 ----------------
// 32-row tile, stage once (38x40 region, origin tx0-4 for float4 alignment),
// two K-loop passes p=0,1. Interior blocks: unguarded float4 staging.
__global__ __launch_bounds__(256) void conv1_mfma(
    const float* __restrict__ in, const half_t* __restrict__ wp,
    const float* __restrict__ bias, half_t* __restrict__ P1)
{
  __shared__ __align__(16) half_t ltile[38 * 40 * 4];   // 12160 B, row stride 40 px
  const int b = blockIdx.z, ty0 = blockIdx.y * 32, tx0 = blockIdx.x * 32;
  const int tid = threadIdx.x;
  const int HW1 = IN_H * IN_W;

  const float* p0 = in + (size_t)b * 3 * HW1;
  const bool interior = (blockIdx.x >= 1) && (blockIdx.x <= 30) &&
                        (blockIdx.y >= 1) && (blockIdx.y <= 22);
  if (interior) {
    for (int i = tid; i < 380; i += 256) {              // 38 rows x 10 float4
      int r = i / 10, c4 = i - r * 10;
      const float* pr = p0 + (size_t)(ty0 - 3 + r) * IN_W + (tx0 - 4 + 4 * c4);
      float4 v0 = *(const float4*)(pr);
      float4 v1 = *(const float4*)(pr + HW1);
      float4 v2 = *(const float4*)(pr + 2 * HW1);
      PK4 a0, a1, a2, a3;
      a0.h[0] = (half_t)v0.x; a0.h[1] = (half_t)v1.x; a0.h[2] = (half_t)v2.x; a0.h[3] = (half_t)0.f;
      a1.h[0] = (half_t)v0.y; a1.h[1] = (half_t)v1.y; a1.h[2] = (half_t)v2.y; a1.h[3] = (half_t)0.f;
      a2.h[0] = (half_t)v0.z; a2.h[1] = (half_t)v1.z; a2.h[2] = (half_t)v2.z; a2.h[3] = (half_t)0.f;
      a3.h[0] = (half_t)v0.w; a3.h[1] = (half_t)v1.w; a3.h[2] = (half_t)v2.w; a3.h[3] = (half_t)0.f;
      uint4* dst = (uint4*)(ltile + (r * 40 + 4 * c4) * 4);
      dst[0] = make_uint4(a0.u.x, a0.u.y, a1.u.x, a1.u.y);
      dst[1] = make_uint4(a2.u.x, a2.u.y, a3.u.x, a3.u.y);
    }
  } else {
    for (int i = tid; i < 1520; i += 256) {             // 38 rows x 40 cols, guarded
      int r = i / 40, c = i - r * 40;
      int gy = ty0 - 3 + r, gx = tx0 - 4 + c;
      float v0 = 0.f, v1 = 0.f, v2 = 0.f;
      if (gy >= 0 && gy < IN_H && (unsigned)gx < (unsigned)IN_W) {
        size_t o = (size_t)gy * IN_W + gx;
        v0 = p0[o];
        v1 = p0[o + HW1];
        v2 = p0[o + 2 * HW1];
      }
      PK4 pk;
      pk.h[0] = (half_t)v0; pk.h[1] = (half_t)v1;
      pk.h[2] = (half_t)v2; pk.h[3] = (half_t)0.f;
      *(uint2*)(ltile + (r * 40 + c) * 4) = pk.u;
    }
  }
  __syncthreads();

  const int wv = tid >> 6, ln = tid & 63, q = ln >> 4, nl = ln & 15;
  const int cbase = (2 * nl + 2 * q + 1) * 4;           // +1: tile origin tx0-4
  const half_t* wA = wp + nl * 32 + q * 8;

  floatx4 bv[2];
  #pragma unroll
  for (int mt = 0; mt < 2; ++mt)
    #pragma unroll
    for (int r = 0; r < 4; ++r) {
      int oc = mt * 16 + q * 4 + r;
      bv[mt][r] = (oc < 20) ? bias[oc] : 0.f;
    }
  const int pc = (tx0 >> 1) + nl;

  #pragma unroll
  for (int p = 0; p < 2; ++p) {
    const int rbase = p * 16 + 4 * wv;            // ltile row of this pass/wave
    U8 frag[4][2];
    #pragma unroll
    for (int d = 0; d < 4; ++d) {
      const half_t* rp = ltile + (rbase + d) * 160 + cbase;
      #pragma unroll
      for (int phx = 0; phx < 2; ++phx) {
        frag[d][phx].u[0] = *(const uint2*)(rp + phx * 4);
        frag[d][phx].u[1] = *(const uint2*)(rp + phx * 4 + 4);
      }
    }
    half8 Abuf[2][2];
    Abuf[0][0] = *(const half8*)(wA);
    Abuf[0][1] = *(const half8*)(wA + 512);
    floatx4 acc[2][8];
    #pragma unroll
    for (int mt = 0; mt < 2; ++mt)
      #pragma unroll
      for (int j = 0; j < 8; ++j) acc[mt][j] = (floatx4){0.f, 0.f, 0.f, 0.f};

    #pragma unroll
    for (int ky = 0; ky < 7; ++ky) {
      if (ky < 6) {
        Abuf[(ky + 1) & 1][0] = *(const half8*)(wA + (ky + 1) * 1024);
        Abuf[(ky + 1) & 1][1] = *(const half8*)(wA + (ky + 1) * 1024 + 512);
      }
      #pragma unroll
      for (int j = 0; j < 8; ++j) {
        const int g = j >> 2, ph = j & 3, phy = ph >> 1, phx = ph & 1;
        half8 B = frag[(2 * g + phy + ky) & 3][phx].v;
        acc[0][j] = __builtin_amdgcn_mfma_f32_16x16x32_f16(Abuf[ky & 1][0], B, acc[0][j], 0, 0, 0);
        acc[1][j] = __builtin_amdgcn_mfma_f32_16x16x32_f16(Abuf[ky & 1][1], B, acc[1][j], 0, 0, 0);
      }
      if (ky < 6) {                               // slide: ltile row rbase+ky+4 -> slot ky&3
        const half_t* rp = ltile + (rbase + ky + 4) * 160 + cbase;
        #pragma unroll
        for (int phx = 0; phx < 2; ++phx) {
          frag[ky & 3][phx].u[0] = *(const uint2*)(rp + phx * 4);
          frag[ky & 3][phx].u[1] = *(const uint2*)(rp + phx * 4 + 4);
        }
      }
    }

    const int pr0 = (ty0 >> 1) + 8 * p + 2 * wv;
    #pragma unroll
    for (int g = 0; g < 2; ++g) {
      size_t pxbase = (((size_t)b * P1H + pr0 + g) * P1W + pc) * 24;
      PK4 pk0;
      #pragma unroll
      for (int r = 0; r < 4; ++r) {
        float x = fmaxf(fmaxf(acc[0][g * 4 + 0][r], acc[0][g * 4 + 1][r]),
                        fmaxf(acc[0][g * 4 + 2][r], acc[0][g * 4 + 3][r]));
        pk0.h[r] = (half_t)fmaxf(x + bv[0][r], 0.f);
      }
      *(uint2*)(P1 + pxbase + q * 4) = pk0.u;           // oc 0..15
      if (q < 2) {                                      // oc 16..19 real, 20..23 = 0
        PK4 pk1;
        #pragma unroll
        for (int r = 0; r < 4; ++r) {
          float x = fmaxf(fmaxf(acc[1][g * 4 + 0][r], acc[1][g * 4 + 1][r]),
                          fmaxf(acc[1][g * 4 + 2][r], acc[1][g * 4 + 3][r]));
          pk1.h[r] = (half_t)fmaxf(x + bv[1][r], 0.f);
        }
        *(uint2*)(P1 + pxbase + 16 + q * 4) = pk1.u;
      }
    }
  }
}

// ---------------- conv2 (20->40, 5x5) MFMA + relu + pool -> P2 f16 NHWC56 ----------------
// K-folded: per ky, taps kx=0..4 are one contiguous 120-half span in the
// NHWC24 row -> 4 K=32 steps. B = lin[row*864 + (2nl+phx)*24 + kk*32 + q*8]
// (16B-aligned). Slots with ch>=20 or pixel>=5 carry zero weights; span
// tail (row 19, px 36) lands in the 16-half zeroed LDS tail.
__global__ __launch_bounds__(256, 2) void conv2_mfma(
    const half_t* __restrict__ P1, const half_t* __restrict__ wp,
    const float* __restrict__ bias, half_t* __restrict__ P2)
{
  __shared__ __align__(16) half_t lin[20 * 36 * 24 + 16];   // 34592 B
  const int b = blockIdx.z, ty0 = blockIdx.y * 16, tx0 = blockIdx.x * 32;
  const int tid = threadIdx.x;
  if (tid < 16) lin[20 * 36 * 24 + tid] = (half_t)0.f;
  for (int i = tid; i < 2160; i += 256) {              // 720 px x 3 uint4
    int px = i / 3, part = i - px * 3;
    int row = px / 36, col = px - row * 36;
    int gy = ty0 - 2 + row, gx = tx0 - 2 + col;
    uint4 v = make_uint4(0, 0, 0, 0);
    if (gy >= 0 && gy < P1H && (unsigned)gx < (unsigned)P1W)
      v = *(const uint4*)(P1 + (((size_t)b * P1H + gy) * P1W + gx) * 24 + part * 8);
    *(uint4*)(lin + px * 24 + part * 8) = v;
  }
  __syncthreads();

  const int wv = tid >> 6, ln = tid & 63, q = ln >> 4, nl = ln & 15;
  const half_t* cb0 = lin + 2 * nl * 24 + q * 8;       // span base, phx=0
  const half_t* wA = wp + nl * 32 + q * 8;

  floatx4 acc[3][8];
  #pragma unroll
  for (int mt = 0; mt < 3; ++mt)
    #pragma unroll
    for (int j = 0; j < 8; ++j) acc[mt][j] = (floatx4){0.f, 0.f, 0.f, 0.f};

  #pragma unroll
  for (int ky = 0; ky < 5; ++ky) {
    #pragma unroll
    for (int kk = 0; kk < 4; ++kk) {
      const half_t* wt = wA + (ky * 4 + kk) * 1536;
      half8 A0 = *(const half8*)(wt);
      half8 A1 = *(const half8*)(wt + 512);
      half8 A2 = *(const half8*)(wt + 1024);
      #pragma unroll
      for (int j = 0; j < 8; ++j) {
        const int g = j >> 2, phy = (j >> 1) & 1, phx = j & 1;
        half8 B = *(const half8*)(cb0 + (4 * wv + 2 * g + phy + ky) * 864 + phx * 24 + kk * 32);
        acc[0][j] = __builtin_amdgcn_mfma_f32_16x16x32_f16(A0, B, acc[0][j], 0, 0, 0);
        acc[1][j] = __builtin_amdgcn_mfma_f32_16x16x32_f16(A1, B, acc[1][j], 0, 0, 0);
        acc[2][j] = __builtin_amdgcn_mfma_f32_16x16x32_f16(A2, B, acc[2][j], 0, 0, 0);
      }
    }
  }

  floatx4 bv[3];
  #pragma unroll
  for (int mt = 0; mt < 3; ++mt)
    #pragma unroll
    for (int r = 0; r < 4; ++r) {
      int oc = mt * 16 + q * 4 + r;
      bv[mt][r] = (oc < 40) ? bias[oc] : 0.f;
    }
  const int pr0 = (ty0 >> 1) + 2 * wv;
  const int pc = (tx0 >> 1) + nl;
  #pragma unroll
  for (int g = 0; g < 2; ++g) {
    size_t pxbase = (((size_t)b * P2H + pr0 + g) * P2W + pc) * 56;
    #pragma unroll
    for (int mt = 0; mt < 3; ++mt) {
      PK4 pk;
      #pragma unroll
      for (int r = 0; r < 4; ++r) {
        float x = fmaxf(fmaxf(acc[mt][g * 4 + 0][r], acc[mt][g * 4 + 1][r]),
                        fmaxf(acc[mt][g * 4 + 2][r], acc[mt][g * 4 + 3][r]));
        pk.h[r] = (half_t)fmaxf(x + bv[mt][r], 0.f);   // oc 40..47: 0+0 -> 0 pad
      }
      *(uint2*)(P2 + pxbase + mt * 16 + q * 4) = pk.u;
    }
    if (q == 0)
      *(uint4*)(P2 + pxbase + 48) = make_uint4(0, 0, 0, 0);  // halves 48..55 = 0
  }
}

// ---------------- conv3 (40->20, 5x5) MFMA + relu -> X3 f16 NHWC24 ----------------
// P2 records 56 halves (40 real + 16 zero). Window frag[2][6][2cb] + A prefetch.
__global__ __launch_bounds__(256, 2) void conv3_mfma(
    const half_t* __restrict__ P2, const half_t* __restrict__ wp,
    const float* __restrict__ bias, half_t* __restrict__ X3)
{
  __shared__ __align__(16) half_t lin[12 * 36 * 56 + 16];   // 48416 B
  const int b = blockIdx.z, ty0 = blockIdx.y * 8, tx0 = blockIdx.x * 32;
  const int tid = threadIdx.x;
  if (tid < 16) lin[12 * 36 * 56 + tid] = (half_t)0.f;
  for (int i = tid; i < 3024; i += 256) {              // 432 px x 7 uint4
    int px = i / 7, part = i - px * 7;
    int row = px / 36, col = px - row * 36;
    int gy = ty0 - 2 + row, gx = tx0 - 2 + col;
    uint4 v = make_uint4(0, 0, 0, 0);
    if (gy >= 0 && gy < P2H && (unsigned)gx < (unsigned)P2W)
      v = *(const uint4*)(P2 + (((size_t)b * P2H + gy) * P2W + gx) * 56 + part * 8);
    *(uint4*)(lin + px * 56 + part * 8) = v;
  }
  __syncthreads();

  const int wv = tid >> 6, ln = tid & 63, q = ln >> 4, nl = ln & 15;
  const int cbase = 2 * nl * 56 + q * 8;               // + row*2016 + c*56 + cb*32
  half8 frag[2][6][2];
  #pragma unroll
  for (int c = 0; c < 6; ++c)
    #pragma unroll
    for (int cb = 0; cb < 2; ++cb) {
      frag[0][c][cb] = *(const half8*)(lin + (2 * wv + 0) * 2016 + cbase + c * 56 + cb * 32);
      frag[1][c][cb] = *(const half8*)(lin + (2 * wv + 1) * 2016 + cbase + c * 56 + cb * 32);
    }
  const half_t* wA = wp + nl * 64 + q * 8;
  half8 Abuf[2][2][2];                                 // [parity][mt][cb]
  #pragma unroll
  for (int mt = 0; mt < 2; ++mt)
    #pragma unroll
    for (int cb = 0; cb < 2; ++cb)
      Abuf[0][mt][cb] = *(const half8*)(wA + mt * 1024 + cb * 32);
  floatx4 acc[2][4];
  #pragma unroll
  for (int mt = 0; mt < 2; ++mt)
    #pragma unroll
    for (int j = 0; j < 4; ++j) acc[mt][j] = (floatx4){0.f, 0.f, 0.f, 0.f};

  #pragma unroll
  for (int ky = 0; ky < 5; ++ky) {
    #pragma unroll
    for (int kx = 0; kx < 5; ++kx) {
      const int tap = ky * 5 + kx;
      if (tap < 24) {
        #pragma unroll
        for (int mt = 0; mt < 2; ++mt)
          #pragma unroll
          for (int cb = 0; cb < 2; ++cb)
            Abuf[(tap + 1) & 1][mt][cb] =
                *(const half8*)(wA + (tap + 1) * 2048 + mt * 1024 + cb * 32);
      }
      #pragma unroll
      for (int cb = 0; cb < 2; ++cb)
        #pragma unroll
        for (int j = 0; j < 4; ++j) {
          const int phy = j >> 1, phx = j & 1;
          half8 B = frag[(ky + phy) & 1][kx + phx][cb];
          acc[0][j] = __builtin_amdgcn_mfma_f32_16x16x32_f16(Abuf[tap & 1][0][cb], B, acc[0][j], 0, 0, 0);
          acc[1][j] = __builtin_amdgcn_mfma_f32_16x16x32_f16(Abuf[tap & 1][1][cb], B, acc[1][j], 0, 0, 0);
        }
    }
    if (ky < 4) {
      const half_t* rp = lin + (2 * wv + ky + 2) * 2016 + cbase;
      #pragma unroll
      for (int c = 0; c < 6; ++c)
        #pragma unroll
        for (int cb = 0; cb < 2; ++cb)
          frag[ky & 1][c][cb] = *(const half8*)(rp + c * 56 + cb * 32);
    }
  }

  floatx4 bv[2];
  #pragma unroll
  for (int mt = 0; mt < 2; ++mt)
    #pragma unroll
    for (int r = 0; r < 4; ++r) {
      int oc = mt * 16 + q * 4 + r;
      bv[mt][r] = (oc < 20) ? bias[oc] : 0.f;
    }
  #pragma unroll
  for (int j = 0; j < 4; ++j) {
    const int phy = j >> 1, phx = j & 1;
    int y = ty0 + 2 * wv + phy, x = tx0 + 2 * nl + phx;
    size_t pxbase = (((size_t)b * P2H + y) * P2W + x) * 24;
    #pragma unroll
    for (int mt = 0; mt < 2; ++mt) {
      if (mt == 1 && q >= 2) continue;                 // record is 24 halves
      floatx4 v = acc[mt][j];
      PK4 pk;
      #pragma unroll
      for (int r = 0; r < 4; ++r) pk.h[r] = (half_t)fmaxf(v[r] + bv[mt][r], 0.f);
      *(uint2*)(X3 + pxbase + mt * 16 + q * 4) = pk.u; // oc 20..23 auto-zero
    }
  }
}

// ---------------- conv4 (20->10, 5x5) + conv5 (10->1, 1x1) + gray residual + relu ----------------
// K-folded as conv2 (mt=1): 160 MFMA/wave (was 200). X3 records 24 halves.
// Fused epilogue: q-lanes hold the same pixel (different oc) -> per-lane w5
// partial, shfl_xor(16)+shfl_xor(32) reduce, q==0 adds gray + writes out.
__global__ __launch_bounds__(256, 2) void conv4_mfma(
    const half_t* __restrict__ X3, const half_t* __restrict__ wp,
    const float* __restrict__ bias, const float* __restrict__ w5,
    const float* __restrict__ b5, const float* __restrict__ in,
    float* __restrict__ out)
{
  __shared__ __align__(16) half_t lin[20 * 36 * 24 + 16];   // 34592 B
  const int b = blockIdx.z, ty0 = blockIdx.y * 16, tx0 = blockIdx.x * 32;
  const int tid = threadIdx.x;
  if (tid < 16) lin[20 * 36 * 24 + tid] = (half_t)0.f;
  for (int i = tid; i < 2160; i += 256) {
    int px = i / 3, part = i - px * 3;
    int row = px / 36, col = px - row * 36;
    int gy = ty0 - 2 + row, gx = tx0 - 2 + col;
    uint4 v = make_uint4(0, 0, 0, 0);
    if (gy >= 0 && gy < P2H && (unsigned)gx < (unsigned)P2W)
      v = *(const uint4*)(X3 + (((size_t)b * P2H + gy) * P2W + gx) * 24 + part * 8);
    *(uint4*)(lin + px * 24 + part * 8) = v;
  }
  __syncthreads();

  const int wv = tid >> 6, ln = tid & 63, q = ln >> 4, nl = ln & 15;
  const half_t* cb0 = lin + 2 * nl * 24 + q * 8;
  const half_t* wA = wp + nl * 32 + q * 8;

  floatx4 acc[8];
  #pragma unroll
  for (int j = 0; j < 8; ++j) acc[j] = (floatx4){0.f, 0.f, 0.f, 0.f};

  #pragma unroll
  for (int ky = 0; ky < 5; ++ky) {
    #pragma unroll
    for (int kk = 0; kk < 4; ++kk) {
      half8 A = *(const half8*)(wA + (ky * 4 + kk) * 512);
      #pragma unroll
      for (int j = 0; j < 8; ++j) {
        const int g = j >> 2, phy = (j >> 1) & 1, phx = j & 1;
        half8 B = *(const half8*)(cb0 + (4 * wv + 2 * g + phy + ky) * 864 + phx * 24 + kk * 32);
        acc[j] = __builtin_amdgcn_mfma_f32_16x16x32_f16(A, B, acc[j], 0, 0, 0);
      }
    }
  }

  float bv[4], w5v[4];
  #pragma unroll
  for (int r = 0; r < 4; ++r) {
    int oc = q * 4 + r;
    bv[r]  = (oc < 10) ? bias[oc] : 0.f;
    w5v[r] = (oc < 10) ? w5[oc] : 0.f;
  }
  const float b5v = b5[0];
  const float* inb = in + (size_t)b * 3 * (IN_H * IN_W);

  #pragma unroll
  for (int g = 0; g < 2; ++g)
    #pragma unroll
    for (int phy = 0; phy < 2; ++phy) {
      const int y = ty0 + 4 * wv + 2 * g + phy;
      const int x0 = tx0 + 2 * nl;                     // phx=0 pixel; phx=1 is x0+1
      float s0 = 0.f, s1 = 0.f;
      #pragma unroll
      for (int r = 0; r < 4; ++r) {
        s0 += w5v[r] * fmaxf(acc[g * 4 + 2 * phy + 0][r] + bv[r], 0.f);
        s1 += w5v[r] * fmaxf(acc[g * 4 + 2 * phy + 1][r] + bv[r], 0.f);
      }
      s0 += __shfl_xor(s0, 16); s0 += __shfl_xor(s0, 32);
      s1 += __shfl_xor(s1, 16); s1 += __shfl_xor(s1, 32);
      if (q == 0) {
        // gray bilinear: input rows 4y+1,4y+2; cols 4x+1,4x+2 for x = x0, x0+1.
        const size_t cb = (size_t)(4 * y + 1) * IN_W + 4 * x0;
        float g0 = 0.f, g1 = 0.f;
        #pragma unroll
        for (int ch = 0; ch < 3; ++ch) {
          const float coef = (ch == 0) ? 0.299f : ((ch == 1) ? 0.587f : 0.114f);
          const float* qp = inb + (size_t)ch * (IN_H * IN_W);
          float4 a0 = *(const float4*)(qp + cb);
          float4 a1 = *(const float4*)(qp + cb + 4);
          float4 d0 = *(const float4*)(qp + cb + IN_W);
          float4 d1 = *(const float4*)(qp + cb + IN_W + 4);
          g0 += coef * (a0.y + a0.z + d0.y + d0.z);
          g1 += coef * (a1.y + a1.z + d1.y + d1.z);
        }
        float o0 = fmaxf(s0 + b5v + fmaxf(g0 * 0.25f, 0.f), 0.f);
        float o1 = fmaxf(s1 + b5v + fmaxf(g1 * 0.25f, 0.f), 0.f);
        *(float2*)(out + ((size_t)b * P2H + y) * P2W + x0) = make_float2(o0, o1);
      }
    }
}

extern "C" void kernel_launch(void* const* d_in, const int* in_sizes, int n_in,
                              void* d_out, int out_size, void* d_ws, size_t ws_size,
                              hipStream_t stream) {
  const float* input = (const float*)d_in[0];
  const float* w1 = (const float*)d_in[1];  const float* b1 = (const float*)d_in[2];
  const float* w2 = (const float*)d_in[3];  const float* b2 = (const float*)d_in[4];
  const float* w3 = (const float*)d_in[5];  const float* b3 = (const float*)d_in[6];
  const float* w4 = (const float*)d_in[7];  const float* b4 = (const float*)d_in[8];
  const float* w5 = (const float*)d_in[9];  const float* b5 = (const float*)d_in[10];
  float* out = (float*)d_out;
  char* ws = (char*)d_ws;

  half_t* P2h = (half_t*)(ws + OFF_P2);
  half_t* P1h = (half_t*)(ws + OFF_P1);
  half_t* X3h = (half_t*)(ws + OFF_X3);
  half_t* wp2 = (half_t*)(ws + OFF_W2);
  half_t* wp3 = (half_t*)(ws + OFF_W3);
  half_t* wp4 = (half_t*)(ws + OFF_W4);
  half_t* wp1 = (half_t*)(ws + OFF_W1);

  pack_weights<<<388, 256, 0, stream>>>(w2, w3, w4, w1, wp2, wp3, wp4, wp1);
  conv1_mfma<<<dim3(32, 24, 8), 256, 0, stream>>>(input, wp1, b1, P1h);
  conv2_mfma<<<dim3(16, 24, 8), 256, 0, stream>>>(P1h, wp2, b2, P2h);
  conv3_mfma<<<dim3(8, 24, 8), 256, 0, stream>>>(P2h, wp3, b3, X3h);
  conv4_mfma<<<dim3(8, 12, 8), 256, 0, stream>>>(X3h, wp4, b4, w5, b5, input, out);
}

// Round 9
// 329.209 us; speedup vs baseline: 1.4339x; 1.1094x over previous
//
#include <hip/hip_runtime.h>

// Res_MCNN_branch2 on gfx950 — all convs f16 MFMA implicit-GEMM (16x16x32).
// R18 = R17 (365 µs) + two fixes:
// (1) conv1 interior staging: 760 float2-pair items, ONE uint4 LDS write at
//     byte 16*i (linear, conflict-free). R10's 2x-uint4-at-32B-stride wrote
//     to only half the banks per instruction -> 6.39M conflict cycles.
// (2) P2 -> NHWC48 (40 real + 8 pad) and conv3 K-folded like R17's conv2:
//     per ky the 5 taps are one contiguous 240-half span -> 8 K=32 steps
//     (was 10) -> 320 MFMA/wave (was 400); frag window deleted; conv2's
//     mt=0..2 epilogue covers exactly 48 oc (zero-store gone, WRITE -14%).
// Failure ledger (conv2, all reverted): R11 gload_lds DMA (22x FETCH),
// R12 multi-tile (L2 thrash), R14 g-split (spill), R15 2-row waves (2x
// overhead), R16 direct-global (spill). Rule: shrink state, keep the
// single-K-loop stage->barrier->compute shape, only reduce MFMA count.
// Layouts: P1 NHWC24, P2 NHWC48, X3 NHWC24. conv4+conv5 fused (R13).

typedef _Float16 half_t;
typedef _Float16 half8 __attribute__((ext_vector_type(8)));
typedef float floatx4 __attribute__((ext_vector_type(4)));

#define IN_H 768
#define IN_W 1024
#define P1H 384
#define P1W 512
#define P2H 192
#define P2W 256

// workspace offsets (bytes)
#define OFF_P2 0ULL                 // f16 [8][192][256][48] = 37,748,736
#define OFF_P1 44040192ULL          // f16 [8][384][512][24] = 75,497,472
#define OFF_X3 44040192ULL          // reuse P1 region after conv2
#define OFF_W2 119537664ULL         // f16 [5][4][48][32] = 30,720 el (K-folded)
#define OFF_W3 119599104ULL         // f16 [5][8][32][32] = 40,960 el (K-folded)
#define OFF_W4 119681024ULL         // f16 [5][4][16][32] = 10,240 el (K-folded)
#define OFF_W1 119701504ULL         // f16 [7][32][32]    = 7,168 el

union PK4 { half_t h[4]; uint2 u; };
union U8 { half8 v; uint2 u[2]; };

// ---------------- weight pre-pack (fp32 OIHW -> f16 packed, linear) ----------------
__global__ __launch_bounds__(256) void pack_weights(
    const float* __restrict__ w2, const float* __restrict__ w3,
    const float* __restrict__ w4, const float* __restrict__ w1,
    half_t* __restrict__ wp2, half_t* __restrict__ wp3, half_t* __restrict__ wp4,
    half_t* __restrict__ wp1)
{
  int t = blockIdx.x * 256 + threadIdx.x;
  if (t < 30720) {                       // conv2 K-folded: [5 ky][4 kk][48 oc][32 k]
    int ky = t / 6144, r = t % 6144;
    int kk = r / 1536, r2 = r % 1536, oc = r2 >> 5, k = r2 & 31;
    int o = kk * 32 + k, p = o / 24, c = o % 24;   // pixel offset p (=kx), channel c
    float v = (oc < 40 && c < 20 && p < 5) ? w2[(oc * 20 + c) * 25 + ky * 5 + p] : 0.f;
    wp2[t] = (half_t)v;
  } else if (t < 71680) {                // conv3 K-folded: [5 ky][8 kk][32 oc][32 k]
    int u = t - 30720;
    int ky = u / 8192, r = u % 8192;
    int kk = r / 1024, r2 = r % 1024, oc = r2 >> 5, k = r2 & 31;
    int o = kk * 32 + k, p = o / 48, c = o % 48;   // pixel p, channel c in NHWC48
    float v = (oc < 20 && c < 40 && p < 5) ? w3[(oc * 40 + c) * 25 + ky * 5 + p] : 0.f;
    wp3[u] = (half_t)v;
  } else if (t < 81920) {                // conv4 K-folded: [5 ky][4 kk][16 oc][32 k]
    int u = t - 71680;
    int ky = u / 2048, r = u % 2048;
    int kk = r / 512, r2 = r % 512, oc = r2 >> 5, k = r2 & 31;
    int o = kk * 32 + k, p = o / 24, c = o % 24;
    float v = (oc < 10 && c < 20 && p < 5) ? w4[(oc * 20 + c) * 25 + ky * 5 + p] : 0.f;
    wp4[u] = (half_t)v;
  } else if (t < 89088) {                // conv1: [7][32][32], k = kx*4+c (unchanged)
    int u = t - 81920;
    int ky = u / 1024, r = u % 1024, oc = r >> 5, k = r & 31;
    int kx = k >> 2, c = k & 3;
    float v = (oc < 20 && c < 3 && kx < 7) ? w1[((oc * 3 + c) * 7 + ky) * 7 + kx] : 0.f;
    wp1[u] = (half_t)v;
  }
}

// ---------------- conv1 (3->20, 7x7, pad 3) MFMA + relu + pool -> P1 f16 NHWC24 ----------------
// 32-row tile, stage once (38x40 region, origin tx0-4), two K-loop passes.
// Interior: float2-pair items -> one uint4 LDS write at byte 16*i (linear,
// bank-conflict-free; the R10 2x-uint4/32B-stride pattern used half the banks).
__global__ __launch_bounds__(256) void conv1_mfma(
    const float* __restrict__ in, const half_t* __restrict__ wp,
    const float* __restrict__ bias, half_t* __restrict__ P1)
{
  __shared__ __align__(16) half_t ltile[38 * 40 * 4];   // 12160 B, row stride 40 px
  const int b = blockIdx.z, ty0 = blockIdx.y * 32, tx0 = blockIdx.x * 32;
  const int tid = threadIdx.x;
  const int HW1 = IN_H * IN_W;

  const float* p0 = in + (size_t)b * 3 * HW1;
  const bool interior = (blockIdx.x >= 1) && (blockIdx.x <= 30) &&
                        (blockIdx.y >= 1) && (blockIdx.y <= 22);
  if (interior) {
    for (int i = tid; i < 760; i += 256) {              // 38 rows x 20 float2-pairs
      int r = i / 20, c2 = i - r * 20;
      const float* pr = p0 + (size_t)(ty0 - 3 + r) * IN_W + (tx0 - 4 + 2 * c2);
      float2 v0 = *(const float2*)(pr);
      float2 v1 = *(const float2*)(pr + HW1);
      float2 v2 = *(const float2*)(pr + 2 * HW1);
      PK4 a0, a1;
      a0.h[0] = (half_t)v0.x; a0.h[1] = (half_t)v1.x; a0.h[2] = (half_t)v2.x; a0.h[3] = (half_t)0.f;
      a1.h[0] = (half_t)v0.y; a1.h[1] = (half_t)v1.y; a1.h[2] = (half_t)v2.y; a1.h[3] = (half_t)0.f;
      *(uint4*)(ltile + (r * 40 + 2 * c2) * 4) =
          make_uint4(a0.u.x, a0.u.y, a1.u.x, a1.u.y);   // byte 16*i: linear
    }
  } else {
    for (int i = tid; i < 1520; i += 256) {             // 38 rows x 40 cols, guarded
      int r = i / 40, c = i - r * 40;
      int gy = ty0 - 3 + r, gx = tx0 - 4 + c;
      float v0 = 0.f, v1 = 0.f, v2 = 0.f;
      if (gy >= 0 && gy < IN_H && (unsigned)gx < (unsigned)IN_W) {
        size_t o = (size_t)gy * IN_W + gx;
        v0 = p0[o];
        v1 = p0[o + HW1];
        v2 = p0[o + 2 * HW1];
      }
      PK4 pk;
      pk.h[0] = (half_t)v0; pk.h[1] = (half_t)v1;
      pk.h[2] = (half_t)v2; pk.h[3] = (half_t)0.f;
      *(uint2*)(ltile + (r * 40 + c) * 4) = pk.u;
    }
  }
  __syncthreads();

  const int wv = tid >> 6, ln = tid & 63, q = ln >> 4, nl = ln & 15;
  const int cbase = (2 * nl + 2 * q + 1) * 4;           // +1: tile origin tx0-4
  const half_t* wA = wp + nl * 32 + q * 8;

  floatx4 bv[2];
  #pragma unroll
  for (int mt = 0; mt < 2; ++mt)
    #pragma unroll
    for (int r = 0; r < 4; ++r) {
      int oc = mt * 16 + q * 4 + r;
      bv[mt][r] = (oc < 20) ? bias[oc] : 0.f;
    }
  const int pc = (tx0 >> 1) + nl;

  #pragma unroll
  for (int p = 0; p < 2; ++p) {
    const int rbase = p * 16 + 4 * wv;            // ltile row of this pass/wave
    U8 frag[4][2];
    #pragma unroll
    for (int d = 0; d < 4; ++d) {
      const half_t* rp = ltile + (rbase + d) * 160 + cbase;
      #pragma unroll
      for (int phx = 0; phx < 2; ++phx) {
        frag[d][phx].u[0] = *(const uint2*)(rp + phx * 4);
        frag[d][phx].u[1] = *(const uint2*)(rp + phx * 4 + 4);
      }
    }
    half8 Abuf[2][2];
    Abuf[0][0] = *(const half8*)(wA);
    Abuf[0][1] = *(const half8*)(wA + 512);
    floatx4 acc[2][8];
    #pragma unroll
    for (int mt = 0; mt < 2; ++mt)
      #pragma unroll
      for (int j = 0; j < 8; ++j) acc[mt][j] = (floatx4){0.f, 0.f, 0.f, 0.f};

    #pragma unroll
    for (int ky = 0; ky < 7; ++ky) {
      if (ky < 6) {
        Abuf[(ky + 1) & 1][0] = *(const half8*)(wA + (ky + 1) * 1024);
        Abuf[(ky + 1) & 1][1] = *(const half8*)(wA + (ky + 1) * 1024 + 512);
      }
      #pragma unroll
      for (int j = 0; j < 8; ++j) {
        const int g = j >> 2, ph = j & 3, phy = ph >> 1, phx = ph & 1;
        half8 B = frag[(2 * g + phy + ky) & 3][phx].v;
        acc[0][j] = __builtin_amdgcn_mfma_f32_16x16x32_f16(Abuf[ky & 1][0], B, acc[0][j], 0, 0, 0);
        acc[1][j] = __builtin_amdgcn_mfma_f32_16x16x32_f16(Abuf[ky & 1][1], B, acc[1][j], 0, 0, 0);
      }
      if (ky < 6) {                               // slide: ltile row rbase+ky+4 -> slot ky&3
        const half_t* rp = ltile + (rbase + ky + 4) * 160 + cbase;
        #pragma unroll
        for (int phx = 0; phx < 2; ++phx) {
          frag[ky & 3][phx].u[0] = *(const uint2*)(rp + phx * 4);
          frag[ky & 3][phx].u[1] = *(const uint2*)(rp + phx * 4 + 4);
        }
      }
    }

    const int pr0 = (ty0 >> 1) + 8 * p + 2 * wv;
    #pragma unroll
    for (int g = 0; g < 2; ++g) {
      size_t pxbase = (((size_t)b * P1H + pr0 + g) * P1W + pc) * 24;
      PK4 pk0;
      #pragma unroll
      for (int r = 0; r < 4; ++r) {
        float x = fmaxf(fmaxf(acc[0][g * 4 + 0][r], acc[0][g * 4 + 1][r]),
                        fmaxf(acc[0][g * 4 + 2][r], acc[0][g * 4 + 3][r]));
        pk0.h[r] = (half_t)fmaxf(x + bv[0][r], 0.f);
      }
      *(uint2*)(P1 + pxbase + q * 4) = pk0.u;           // oc 0..15
      if (q < 2) {                                      // oc 16..19 real, 20..23 = 0
        PK4 pk1;
        #pragma unroll
        for (int r = 0; r < 4; ++r) {
          float x = fmaxf(fmaxf(acc[1][g * 4 + 0][r], acc[1][g * 4 + 1][r]),
                          fmaxf(acc[1][g * 4 + 2][r], acc[1][g * 4 + 3][r]));
          pk1.h[r] = (half_t)fmaxf(x + bv[1][r], 0.f);
        }
        *(uint2*)(P1 + pxbase + 16 + q * 4) = pk1.u;
      }
    }
  }
}

// ---------------- conv2 (20->40, 5x5) MFMA + relu + pool -> P2 f16 NHWC48 ----------------
// K-folded (R17): 4 K=32 steps per ky over the contiguous 120-half span.
// Output NHWC48: mt=0..2 covers exactly 48 oc (40 real + 8 zero-weight pad).
__global__ __launch_bounds__(256, 2) void conv2_mfma(
    const half_t* __restrict__ P1, const half_t* __restrict__ wp,
    const float* __restrict__ bias, half_t* __restrict__ P2)
{
  __shared__ __align__(16) half_t lin[20 * 36 * 24 + 16];   // 34592 B
  const int b = blockIdx.z, ty0 = blockIdx.y * 16, tx0 = blockIdx.x * 32;
  const int tid = threadIdx.x;
  if (tid < 16) lin[20 * 36 * 24 + tid] = (half_t)0.f;
  for (int i = tid; i < 2160; i += 256) {              // 720 px x 3 uint4
    int px = i / 3, part = i - px * 3;
    int row = px / 36, col = px - row * 36;
    int gy = ty0 - 2 + row, gx = tx0 - 2 + col;
    uint4 v = make_uint4(0, 0, 0, 0);
    if (gy >= 0 && gy < P1H && (unsigned)gx < (unsigned)P1W)
      v = *(const uint4*)(P1 + (((size_t)b * P1H + gy) * P1W + gx) * 24 + part * 8);
    *(uint4*)(lin + px * 24 + part * 8) = v;
  }
  __syncthreads();

  const int wv = tid >> 6, ln = tid & 63, q = ln >> 4, nl = ln & 15;
  const half_t* cb0 = lin + 2 * nl * 24 + q * 8;       // span base, phx=0
  const half_t* wA = wp + nl * 32 + q * 8;

  floatx4 acc[3][8];
  #pragma unroll
  for (int mt = 0; mt < 3; ++mt)
    #pragma unroll
    for (int j = 0; j < 8; ++j) acc[mt][j] = (floatx4){0.f, 0.f, 0.f, 0.f};

  #pragma unroll
  for (int ky = 0; ky < 5; ++ky) {
    #pragma unroll
    for (int kk = 0; kk < 4; ++kk) {
      const half_t* wt = wA + (ky * 4 + kk) * 1536;
      half8 A0 = *(const half8*)(wt);
      half8 A1 = *(const half8*)(wt + 512);
      half8 A2 = *(const half8*)(wt + 1024);
      #pragma unroll
      for (int j = 0; j < 8; ++j) {
        const int g = j >> 2, phy = (j >> 1) & 1, phx = j & 1;
        half8 B = *(const half8*)(cb0 + (4 * wv + 2 * g + phy + ky) * 864 + phx * 24 + kk * 32);
        acc[0][j] = __builtin_amdgcn_mfma_f32_16x16x32_f16(A0, B, acc[0][j], 0, 0, 0);
        acc[1][j] = __builtin_amdgcn_mfma_f32_16x16x32_f16(A1, B, acc[1][j], 0, 0, 0);
        acc[2][j] = __builtin_amdgcn_mfma_f32_16x16x32_f16(A2, B, acc[2][j], 0, 0, 0);
      }
    }
  }

  floatx4 bv[3];
  #pragma unroll
  for (int mt = 0; mt < 3; ++mt)
    #pragma unroll
    for (int r = 0; r < 4; ++r) {
      int oc = mt * 16 + q * 4 + r;
      bv[mt][r] = (oc < 40) ? bias[oc] : 0.f;
    }
  const int pr0 = (ty0 >> 1) + 2 * wv;
  const int pc = (tx0 >> 1) + nl;
  #pragma unroll
  for (int g = 0; g < 2; ++g) {
    size_t pxbase = (((size_t)b * P2H + pr0 + g) * P2W + pc) * 48;
    #pragma unroll
    for (int mt = 0; mt < 3; ++mt) {
      PK4 pk;
      #pragma unroll
      for (int r = 0; r < 4; ++r) {
        float x = fmaxf(fmaxf(acc[mt][g * 4 + 0][r], acc[mt][g * 4 + 1][r]),
                        fmaxf(acc[mt][g * 4 + 2][r], acc[mt][g * 4 + 3][r]));
        pk.h[r] = (half_t)fmaxf(x + bv[mt][r], 0.f);   // oc 40..47: 0+0 -> 0 pad
      }
      *(uint2*)(P2 + pxbase + mt * 16 + q * 4) = pk.u;
    }
  }
}

// ---------------- conv3 (40->20, 5x5) MFMA + relu -> X3 f16 NHWC24 ----------------
// K-folded: per ky the 5 taps are one contiguous 240-half NHWC48 span ->
// 8 K=32 steps (was 10). Weights [5][8][32][32], slot o -> (px o/48, ch o%48),
// zero where ch>=40 or px>=5. Worst read = half 20751 < 20752 (zero tail).
__global__ __launch_bounds__(256, 2) void conv3_mfma(
    const half_t* __restrict__ P2, const half_t* __restrict__ wp,
    const float* __restrict__ bias, half_t* __restrict__ X3)
{
  __shared__ __align__(16) half_t lin[12 * 36 * 48 + 16];   // 41504 B
  const int b = blockIdx.z, ty0 = blockIdx.y * 8, tx0 = blockIdx.x * 32;
  const int tid = threadIdx.x;
  if (tid < 16) lin[12 * 36 * 48 + tid] = (half_t)0.f;
  for (int i = tid; i < 2592; i += 256) {              // 432 px x 6 uint4
    int px = i / 6, part = i - px * 6;
    int row = px / 36, col = px - row * 36;
    int gy = ty0 - 2 + row, gx = tx0 - 2 + col;
    uint4 v = make_uint4(0, 0, 0, 0);
    if (gy >= 0 && gy < P2H && (unsigned)gx < (unsigned)P2W)
      v = *(const uint4*)(P2 + (((size_t)b * P2H + gy) * P2W + gx) * 48 + part * 8);
    *(uint4*)(lin + px * 48 + part * 8) = v;
  }
  __syncthreads();

  const int wv = tid >> 6, ln = tid & 63, q = ln >> 4, nl = ln & 15;
  const half_t* cb0 = lin + 2 * nl * 48 + q * 8;       // span base, phx=0
  const half_t* wA = wp + nl * 32 + q * 8;

  floatx4 acc[2][4];
  #pragma unroll
  for (int mt = 0; mt < 2; ++mt)
    #pragma unroll
    for (int j = 0; j < 4; ++j) acc[mt][j] = (floatx4){0.f, 0.f, 0.f, 0.f};

  #pragma unroll
  for (int ky = 0; ky < 5; ++ky) {
    #pragma unroll
    for (int kk = 0; kk < 8; ++kk) {
      const half_t* wt = wA + (ky * 8 + kk) * 1024;
      half8 A0 = *(const half8*)(wt);
      half8 A1 = *(const half8*)(wt + 512);
      #pragma unroll
      for (int j = 0; j < 4; ++j) {
        const int phy = j >> 1, phx = j & 1;
        half8 B = *(const half8*)(cb0 + (2 * wv + phy + ky) * 1728 + phx * 48 + kk * 32);
        acc[0][j] = __builtin_amdgcn_mfma_f32_16x16x32_f16(A0, B, acc[0][j], 0, 0, 0);
        acc[1][j] = __builtin_amdgcn_mfma_f32_16x16x32_f16(A1, B, acc[1][j], 0, 0, 0);
      }
    }
  }

  floatx4 bv[2];
  #pragma unroll
  for (int mt = 0; mt < 2; ++mt)
    #pragma unroll
    for (int r = 0; r < 4; ++r) {
      int oc = mt * 16 + q * 4 + r;
      bv[mt][r] = (oc < 20) ? bias[oc] : 0.f;
    }
  #pragma unroll
  for (int j = 0; j < 4; ++j) {
    const int phy = j >> 1, phx = j & 1;
    int y = ty0 + 2 * wv + phy, x = tx0 + 2 * nl + phx;
    size_t pxbase = (((size_t)b * P2H + y) * P2W + x) * 24;
    #pragma unroll
    for (int mt = 0; mt < 2; ++mt) {
      if (mt == 1 && q >= 2) continue;                 // record is 24 halves
      floatx4 v = acc[mt][j];
      PK4 pk;
      #pragma unroll
      for (int r = 0; r < 4; ++r) pk.h[r] = (half_t)fmaxf(v[r] + bv[mt][r], 0.f);
      *(uint2*)(X3 + pxbase + mt * 16 + q * 4) = pk.u; // oc 20..23 auto-zero
    }
  }
}

// ---------------- conv4 (20->10, 5x5) + conv5 (10->1, 1x1) + gray residual + relu ----------------
// K-folded (R17, mt=1): 160 MFMA/wave. X3 records 24 halves.
// Fused epilogue: q-lanes hold the same pixel (different oc) -> per-lane w5
// partial, shfl_xor(16)+shfl_xor(32) reduce, q==0 adds gray + writes out.
__global__ __launch_bounds__(256, 2) void conv4_mfma(
    const half_t* __restrict__ X3, const half_t* __restrict__ wp,
    const float* __restrict__ bias, const float* __restrict__ w5,
    const float* __restrict__ b5, const float* __restrict__ in,
    float* __restrict__ out)
{
  __shared__ __align__(16) half_t lin[20 * 36 * 24 + 16];   // 34592 B
  const int b = blockIdx.z, ty0 = blockIdx.y * 16, tx0 = blockIdx.x * 32;
  const int tid = threadIdx.x;
  if (tid < 16) lin[20 * 36 * 24 + tid] = (half_t)0.f;
  for (int i = tid; i < 2160; i += 256) {
    int px = i / 3, part = i - px * 3;
    int row = px / 36, col = px - row * 36;
    int gy = ty0 - 2 + row, gx = tx0 - 2 + col;
    uint4 v = make_uint4(0, 0, 0, 0);
    if (gy >= 0 && gy < P2H && (unsigned)gx < (unsigned)P2W)
      v = *(const uint4*)(X3 + (((size_t)b * P2H + gy) * P2W + gx) * 24 + part * 8);
    *(uint4*)(lin + px * 24 + part * 8) = v;
  }
  __syncthreads();

  const int wv = tid >> 6, ln = tid & 63, q = ln >> 4, nl = ln & 15;
  const half_t* cb0 = lin + 2 * nl * 24 + q * 8;
  const half_t* wA = wp + nl * 32 + q * 8;

  floatx4 acc[8];
  #pragma unroll
  for (int j = 0; j < 8; ++j) acc[j] = (floatx4){0.f, 0.f, 0.f, 0.f};

  #pragma unroll
  for (int ky = 0; ky < 5; ++ky) {
    #pragma unroll
    for (int kk = 0; kk < 4; ++kk) {
      half8 A = *(const half8*)(wA + (ky * 4 + kk) * 512);
      #pragma unroll
      for (int j = 0; j < 8; ++j) {
        const int g = j >> 2, phy = (j >> 1) & 1, phx = j & 1;
        half8 B = *(const half8*)(cb0 + (4 * wv + 2 * g + phy + ky) * 864 + phx * 24 + kk * 32);
        acc[j] = __builtin_amdgcn_mfma_f32_16x16x32_f16(A, B, acc[j], 0, 0, 0);
      }
    }
  }

  float bv[4], w5v[4];
  #pragma unroll
  for (int r = 0; r < 4; ++r) {
    int oc = q * 4 + r;
    bv[r]  = (oc < 10) ? bias[oc] : 0.f;
    w5v[r] = (oc < 10) ? w5[oc] : 0.f;
  }
  const float b5v = b5[0];
  const float* inb = in + (size_t)b * 3 * (IN_H * IN_W);

  #pragma unroll
  for (int g = 0; g < 2; ++g)
    #pragma unroll
    for (int phy = 0; phy < 2; ++phy) {
      const int y = ty0 + 4 * wv + 2 * g + phy;
      const int x0 = tx0 + 2 * nl;                     // phx=0 pixel; phx=1 is x0+1
      float s0 = 0.f, s1 = 0.f;
      #pragma unroll
      for (int r = 0; r < 4; ++r) {
        s0 += w5v[r] * fmaxf(acc[g * 4 + 2 * phy + 0][r] + bv[r], 0.f);
        s1 += w5v[r] * fmaxf(acc[g * 4 + 2 * phy + 1][r] + bv[r], 0.f);
      }
      s0 += __shfl_xor(s0, 16); s0 += __shfl_xor(s0, 32);
      s1 += __shfl_xor(s1, 16); s1 += __shfl_xor(s1, 32);
      if (q == 0) {
        // gray bilinear: input rows 4y+1,4y+2; cols 4x+1,4x+2 for x = x0, x0+1.
        const size_t cb = (size_t)(4 * y + 1) * IN_W + 4 * x0;
        float g0 = 0.f, g1 = 0.f;
        #pragma unroll
        for (int ch = 0; ch < 3; ++ch) {
          const float coef = (ch == 0) ? 0.299f : ((ch == 1) ? 0.587f : 0.114f);
          const float* qp = inb + (size_t)ch * (IN_H * IN_W);
          float4 a0 = *(const float4*)(qp + cb);
          float4 a1 = *(const float4*)(qp + cb + 4);
          float4 d0 = *(const float4*)(qp + cb + IN_W);
          float4 d1 = *(const float4*)(qp + cb + IN_W + 4);
          g0 += coef * (a0.y + a0.z + d0.y + d0.z);
          g1 += coef * (a1.y + a1.z + d1.y + d1.z);
        }
        float o0 = fmaxf(s0 + b5v + fmaxf(g0 * 0.25f, 0.f), 0.f);
        float o1 = fmaxf(s1 + b5v + fmaxf(g1 * 0.25f, 0.f), 0.f);
        *(float2*)(out + ((size_t)b * P2H + y) * P2W + x0) = make_float2(o0, o1);
      }
    }
}

extern "C" void kernel_launch(void* const* d_in, const int* in_sizes, int n_in,
                              void* d_out, int out_size, void* d_ws, size_t ws_size,
                              hipStream_t stream) {
  const float* input = (const float*)d_in[0];
  const float* w1 = (const float*)d_in[1];  const float* b1 = (const float*)d_in[2];
  const float* w2 = (const float*)d_in[3];  const float* b2 = (const float*)d_in[4];
  const float* w3 = (const float*)d_in[5];  const float* b3 = (const float*)d_in[6];
  const float* w4 = (const float*)d_in[7];  const float* b4 = (const float*)d_in[8];
  const float* w5 = (const float*)d_in[9];  const float* b5 = (const float*)d_in[10];
  float* out = (float*)d_out;
  char* ws = (char*)d_ws;

  half_t* P2h = (half_t*)(ws + OFF_P2);
  half_t* P1h = (half_t*)(ws + OFF_P1);
  half_t* X3h = (half_t*)(ws + OFF_X3);
  half_t* wp2 = (half_t*)(ws + OFF_W2);
  half_t* wp3 = (half_t*)(ws + OFF_W3);
  half_t* wp4 = (half_t*)(ws + OFF_W4);
  half_t* wp1 = (half_t*)(ws + OFF_W1);

  pack_weights<<<348, 256, 0, stream>>>(w2, w3, w4, w1, wp2, wp3, wp4, wp1);
  conv1_mfma<<<dim3(32, 24, 8), 256, 0, stream>>>(input, wp1, b1, P1h);
  conv2_mfma<<<dim3(16, 24, 8), 256, 0, stream>>>(P1h, wp2, b2, P2h);
  conv3_mfma<<<dim3(8, 24, 8), 256, 0, stream>>>(P2h, wp3, b3, X3h);
  conv4_mfma<<<dim3(8, 12, 8), 256, 0, stream>>>(X3h, wp4, b4, w5, b5, input, out);
}